// Round 1
// baseline (702.111 us; speedup 1.0000x reference)
//
#include <hip/hip_runtime.h>
#include <stdint.h>

// ---------------------------------------------------------------------------
// InvariantPointAttention, N=20000 nodes, E=640000 edges, H=4, S=64, QK=VD=8
//
// Pipeline (all on `stream`):
//   memset(counts) / k_count / k_scan : CSR build.  k_count stores rank[e]
//       (atomic return).
//   k_zfill  : per ORIGINAL edge e (coalesced z stream!): CSR fill
//              (pos = roff[i]+rank[e], atomic-free) PLUS z-projection
//              (z@Wb -> bias staged into logits[pos], z@Wdz -> pz[pos]).
//              The 164 MB z array is read coalesced here instead of being
//              randomly gathered in k_edge (which ran at 1.4 TB/s).
//   k_proj   : tiled per-node projections (32 nodes/block, transposed LDS
//              s-tile): q_s,k_s (bf16 Nx256), q_v,k_v (rot+trans bf16 Nx96),
//              v_s (f32 Nx256), v_loc (raw points f32 Nx96, PLANE layout).
//              out_scalar == v_s and out_vec == raw v_loc exactly
//              (softmax weights sum to 1; R^-1(R(v)+t-t)=v).
//   k_edge   : per CSR edge (1 thread/edge): gather q_s[j],k_v[j] vs
//              k_s[i],q_v[i]; logits[p] += attention terms (bias already
//              staged there by k_zfill).  No z access, no pz write.
//   k_soft   : wave-per-node, register/shuffle only: per-head max+sum
//              (lane-parallel), then weighted pair aggregation with
//              lane=(e4,col) -> out_pair (Nx64), coalesced store.
//   k_out    : assemble feats[448] per node + feats @ Wout + bout -> out
// ---------------------------------------------------------------------------

#define C_SQRT83  1.6329931618554518f   // sqrt(8/3)
#define C_SQRT13  0.5773502691896258f   // sqrt(1/3)
#define C_VEC    -0.04811252243246881f  // -0.5*sqrt(1/108)

__device__ __forceinline__ unsigned short f2bf(float f){
  unsigned u = __float_as_uint(f);
  u += 0x7fffu + ((u >> 16) & 1u);          // round-to-nearest-even
  return (unsigned short)(u >> 16);
}
__device__ __forceinline__ unsigned pack2(float a, float b){
  return (unsigned)f2bf(a) | ((unsigned)f2bf(b) << 16);
}
__device__ __forceinline__ float bflo(unsigned u){ return __uint_as_float(u << 16); }
__device__ __forceinline__ float bfhi(unsigned u){ return __uint_as_float(u & 0xffff0000u); }

__device__ __forceinline__ void quat_rot(float w, float ux, float uy, float uz,
                                         float vx, float vy, float vz,
                                         float& ox, float& oy, float& oz){
  float cx = uy*vz - uz*vy;
  float cy = uz*vx - ux*vz;
  float cz = ux*vy - uy*vx;
  float dx = uy*cz - uz*cy;
  float dy = uz*cx - ux*cz;
  float dz = ux*cy - uy*cx;
  ox = vx + 2.f*(w*cx + dx);
  oy = vy + 2.f*(w*cy + dy);
  oz = vz + 2.f*(w*cz + dz);
}

// -------------------------------- CSR build --------------------------------

__global__ __launch_bounds__(256) void k_count(const int* __restrict__ ei,
                                               unsigned* __restrict__ counts,
                                               unsigned* __restrict__ rank, int ne){
  int e = blockIdx.x*256 + threadIdx.x;
  if (e >= ne) return;
  rank[e] = atomicAdd(&counts[ei[e]], 1u);
}

__global__ __launch_bounds__(256) void k_scan(const unsigned* __restrict__ counts,
                                              unsigned* __restrict__ row_off, int n){
  __shared__ unsigned part[256];
  int t = threadIdx.x;
  int chunk = (n + 255) >> 8;
  int s0 = t*chunk, s1 = min(s0 + chunk, n);
  unsigned sum = 0;
  for (int k = s0; k < s1; ++k) sum += counts[k];
  part[t] = sum; __syncthreads();
  for (int off = 1; off < 256; off <<= 1){
    unsigned v = (t >= off) ? part[t-off] : 0u;
    __syncthreads();
    part[t] += v;
    __syncthreads();
  }
  unsigned run = (t == 0) ? 0u : part[t-1];
  for (int k = s0; k < s1; ++k){
    row_off[k] = run; run += counts[k];
  }
  if (t == 255) row_off[n] = part[255];
}

// ---------------- CSR fill + z-projection (coalesced z stream) --------------
// One thread per ORIGINAL edge e: z[e] read is fully coalesced (the 164 MB
// z array streams at HBM rate instead of being randomly gathered).  Results
// (tiny: 16 B bias + 32 B pz) are scattered to CSR position pos.

__global__ __launch_bounds__(256) void k_zfill(
    const int* __restrict__ ei, const unsigned* __restrict__ rank,
    const unsigned* __restrict__ roff, const float* __restrict__ z,
    const float* __restrict__ Wb,  const float* __restrict__ bb,
    const float* __restrict__ Wdz, const float* __restrict__ bdz,
    unsigned* __restrict__ si, unsigned* __restrict__ sj,
    float* __restrict__ logits, unsigned* __restrict__ pz, int ne)
{
  const int e = blockIdx.x*256 + threadIdx.x;
  if (e >= ne) return;
  const int i = ei[e];
  const unsigned pos = roff[i] + rank[e];
  si[pos] = (unsigned)i;
  sj[pos] = (unsigned)ei[ne + e];

  // ---- bias (z@Wb) and pair (z@Wdz) ----
  float b4[4];  b4[0]=b4[1]=b4[2]=b4[3]=0.f;
  float pacc[16];
  #pragma unroll
  for (int c=0;c<16;c++) pacc[c]=0.f;
  const float* zr = z + (size_t)e*64;
  #pragma unroll
  for (int k4 = 0; k4 < 16; ++k4){
    const float4 zv = *(const float4*)(zr + 4*k4);
    #pragma unroll
    for (int kk = 0; kk < 4; ++kk){
      const int k = 4*k4 + kk;
      const float zk = (kk==0)?zv.x:((kk==1)?zv.y:((kk==2)?zv.z:zv.w));
      const float4 wb = *(const float4*)(Wb + k*4);
      b4[0]+=zk*wb.x; b4[1]+=zk*wb.y; b4[2]+=zk*wb.z; b4[3]+=zk*wb.w;
      const float* wd = Wdz + k*16;
      const float4 w0=*(const float4*)(wd), w1=*(const float4*)(wd+4),
                   w2=*(const float4*)(wd+8), w3=*(const float4*)(wd+12);
      pacc[ 0]+=zk*w0.x; pacc[ 1]+=zk*w0.y; pacc[ 2]+=zk*w0.z; pacc[ 3]+=zk*w0.w;
      pacc[ 4]+=zk*w1.x; pacc[ 5]+=zk*w1.y; pacc[ 6]+=zk*w1.z; pacc[ 7]+=zk*w1.w;
      pacc[ 8]+=zk*w2.x; pacc[ 9]+=zk*w2.y; pacc[10]+=zk*w2.z; pacc[11]+=zk*w2.w;
      pacc[12]+=zk*w3.x; pacc[13]+=zk*w3.y; pacc[14]+=zk*w3.z; pacc[15]+=zk*w3.w;
    }
  }
  #pragma unroll
  for (int c=0;c<16;c++) pacc[c] += bdz[c];
  { uint4 u0, u1;
    u0.x=pack2(pacc[0],pacc[1]);   u0.y=pack2(pacc[2],pacc[3]);
    u0.z=pack2(pacc[4],pacc[5]);   u0.w=pack2(pacc[6],pacc[7]);
    u1.x=pack2(pacc[8],pacc[9]);   u1.y=pack2(pacc[10],pacc[11]);
    u1.z=pack2(pacc[12],pacc[13]); u1.w=pack2(pacc[14],pacc[15]);
    uint4* d = (uint4*)(pz + (size_t)pos*8);
    d[0]=u0; d[1]=u1; }

  // bias staged into logits[pos]; k_edge adds the attention terms on top.
  float4 bo;
  bo.x = C_SQRT13*(b4[0] + bb[0]);
  bo.y = C_SQRT13*(b4[1] + bb[1]);
  bo.z = C_SQRT13*(b4[2] + bb[2]);
  bo.w = C_SQRT13*(b4[3] + bb[3]);
  *(float4*)(logits + (size_t)pos*4) = bo;
}

// ------------------------------ node projections ----------------------------
// Block = 32 nodes, 256 threads.  s tile TRANSPOSED in LDS: stT[k][node].

#define BN 32

__device__ __forceinline__ void pass256(const float* __restrict__ W,
                                        const float stT[64][40], int cg, int sl,
                                        float acc[8][4]){
  #pragma unroll
  for (int i=0;i<8;i++){ acc[i][0]=0.f; acc[i][1]=0.f; acc[i][2]=0.f; acc[i][3]=0.f; }
  #pragma unroll 4
  for (int k = 0; k < 64; ++k){
    const float4 w  = *(const float4*)(W + (size_t)k*256 + cg*4);
    const float4 n0 = *(const float4*)&stT[k][sl*8];
    const float4 n1 = *(const float4*)&stT[k][sl*8+4];
    acc[0][0]+=n0.x*w.x; acc[0][1]+=n0.x*w.y; acc[0][2]+=n0.x*w.z; acc[0][3]+=n0.x*w.w;
    acc[1][0]+=n0.y*w.x; acc[1][1]+=n0.y*w.y; acc[1][2]+=n0.y*w.z; acc[1][3]+=n0.y*w.w;
    acc[2][0]+=n0.z*w.x; acc[2][1]+=n0.z*w.y; acc[2][2]+=n0.z*w.z; acc[2][3]+=n0.z*w.w;
    acc[3][0]+=n0.w*w.x; acc[3][1]+=n0.w*w.y; acc[3][2]+=n0.w*w.z; acc[3][3]+=n0.w*w.w;
    acc[4][0]+=n1.x*w.x; acc[4][1]+=n1.x*w.y; acc[4][2]+=n1.x*w.z; acc[4][3]+=n1.x*w.w;
    acc[5][0]+=n1.y*w.x; acc[5][1]+=n1.y*w.y; acc[5][2]+=n1.y*w.z; acc[5][3]+=n1.y*w.w;
    acc[6][0]+=n1.z*w.x; acc[6][1]+=n1.z*w.y; acc[6][2]+=n1.z*w.z; acc[6][3]+=n1.z*w.w;
    acc[7][0]+=n1.w*w.x; acc[7][1]+=n1.w*w.y; acc[7][2]+=n1.w*w.z; acc[7][3]+=n1.w*w.w;
  }
}

__device__ __forceinline__ void pass96(const float* __restrict__ W,
                                       const float stT[64][40], int cgp, int slp,
                                       float acc[4][4]){
  #pragma unroll
  for (int i=0;i<4;i++){ acc[i][0]=0.f; acc[i][1]=0.f; acc[i][2]=0.f; acc[i][3]=0.f; }
  if (cgp >= 24) return;
  #pragma unroll 4
  for (int k = 0; k < 64; ++k){
    const float4 w = *(const float4*)(W + (size_t)k*96 + cgp*4);
    const float4 nv = *(const float4*)&stT[k][slp*4];
    acc[0][0]+=nv.x*w.x; acc[0][1]+=nv.x*w.y; acc[0][2]+=nv.x*w.z; acc[0][3]+=nv.x*w.w;
    acc[1][0]+=nv.y*w.x; acc[1][1]+=nv.y*w.y; acc[1][2]+=nv.y*w.z; acc[1][3]+=nv.y*w.w;
    acc[2][0]+=nv.z*w.x; acc[2][1]+=nv.z*w.y; acc[2][2]+=nv.z*w.z; acc[2][3]+=nv.z*w.w;
    acc[3][0]+=nv.w*w.x; acc[3][1]+=nv.w*w.y; acc[3][2]+=nv.w*w.z; acc[3][3]+=nv.w*w.w;
  }
}

__global__ __launch_bounds__(256) void k_proj(
    const float* __restrict__ s, const float* __restrict__ quat, const float* __restrict__ trans,
    const float* __restrict__ Wqs, const float* __restrict__ Wks, const float* __restrict__ Wvs,
    const float* __restrict__ Wqv, const float* __restrict__ Wkv, const float* __restrict__ Wvv,
    unsigned* __restrict__ qs, unsigned* __restrict__ ks, float* __restrict__ vs,
    unsigned* __restrict__ qv, unsigned* __restrict__ kv, float* __restrict__ vv, int n)
{
  __shared__ float stT[64][40];    // transposed s tile (k-major), 16B-aligned cols
  __shared__ float pt[BN][97];     // point staging (x:0..31, y:32..63, z:64..95)
  const int tid = threadIdx.x;
  const int node0 = blockIdx.x * BN;

  #pragma unroll
  for (int r = 0; r < 2; ++r){
    const int idx = tid + r*256;          // float4 index
    const int nd = idx >> 4, c4 = idx & 15;
    const int g = node0 + nd;
    float4 v = make_float4(0.f,0.f,0.f,0.f);
    if (g < n) v = *(const float4*)(s + (size_t)g*64 + c4*4);
    stT[c4*4+0][nd]=v.x; stT[c4*4+1][nd]=v.y; stT[c4*4+2][nd]=v.z; stT[c4*4+3][nd]=v.w;
  }
  __syncthreads();

  const int cg = tid & 63, sl = tid >> 6;
  const int cgp = tid & 31, slp = tid >> 5;
  float acc[8][4];

  pass256(Wqs, stT, cg, sl, acc);
  #pragma unroll
  for (int i=0;i<8;i++){
    const int g = node0 + sl*8 + i;
    if (g < n){
      uint2 u; u.x = pack2(acc[i][0],acc[i][1]); u.y = pack2(acc[i][2],acc[i][3]);
      *(uint2*)(qs + (size_t)g*128 + cg*2) = u;
    }
  }
  pass256(Wks, stT, cg, sl, acc);
  #pragma unroll
  for (int i=0;i<8;i++){
    const int g = node0 + sl*8 + i;
    if (g < n){
      uint2 u; u.x = pack2(acc[i][0],acc[i][1]); u.y = pack2(acc[i][2],acc[i][3]);
      *(uint2*)(ks + (size_t)g*128 + cg*2) = u;
    }
  }
  pass256(Wvs, stT, cg, sl, acc);
  #pragma unroll
  for (int i=0;i<8;i++){
    const int g = node0 + sl*8 + i;
    if (g < n){
      float4 f; f.x=acc[i][0]; f.y=acc[i][1]; f.z=acc[i][2]; f.w=acc[i][3];
      *(float4*)(vs + (size_t)g*256 + cg*4) = f;
    }
  }

  float pac[4][4];

  // q_v: rotate + translate -> bf16
  pass96(Wqv, stT, cgp, slp, pac);
  __syncthreads();
  if (cgp < 24){
    #pragma unroll
    for (int i=0;i<4;i++){
      #pragma unroll
      for (int c=0;c<4;c++) pt[slp*4+i][cgp*4+c] = pac[i][c];
    }
  }
  __syncthreads();
  #pragma unroll
  for (int r = 0; r < 2; ++r){
    const int t2 = tid + r*256;
    const int nd = t2 >> 4, pp = t2 & 15;
    const int g = node0 + nd;
    if (g < n){
      const float4 q4 = *(const float4*)(quat + (size_t)g*4);
      const float tx = trans[(size_t)g*3], ty = trans[(size_t)g*3+1], tz = trans[(size_t)g*3+2];
      float x0,y0,z0,x1,y1,z1;
      quat_rot(q4.x,q4.y,q4.z,q4.w, pt[nd][2*pp],   pt[nd][32+2*pp],   pt[nd][64+2*pp],   x0,y0,z0);
      quat_rot(q4.x,q4.y,q4.z,q4.w, pt[nd][2*pp+1], pt[nd][32+2*pp+1], pt[nd][64+2*pp+1], x1,y1,z1);
      x0+=tx; y0+=ty; z0+=tz; x1+=tx; y1+=ty; z1+=tz;
      unsigned* d = qv + (size_t)g*48 + pp*3;
      d[0] = pack2(x0,y0); d[1] = pack2(z0,x1); d[2] = pack2(y1,z1);
    }
  }

  // k_v: rotate + translate -> bf16
  pass96(Wkv, stT, cgp, slp, pac);
  __syncthreads();
  if (cgp < 24){
    #pragma unroll
    for (int i=0;i<4;i++){
      #pragma unroll
      for (int c=0;c<4;c++) pt[slp*4+i][cgp*4+c] = pac[i][c];
    }
  }
  __syncthreads();
  #pragma unroll
  for (int r = 0; r < 2; ++r){
    const int t2 = tid + r*256;
    const int nd = t2 >> 4, pp = t2 & 15;
    const int g = node0 + nd;
    if (g < n){
      const float4 q4 = *(const float4*)(quat + (size_t)g*4);
      const float tx = trans[(size_t)g*3], ty = trans[(size_t)g*3+1], tz = trans[(size_t)g*3+2];
      float x0,y0,z0,x1,y1,z1;
      quat_rot(q4.x,q4.y,q4.z,q4.w, pt[nd][2*pp],   pt[nd][32+2*pp],   pt[nd][64+2*pp],   x0,y0,z0);
      quat_rot(q4.x,q4.y,q4.z,q4.w, pt[nd][2*pp+1], pt[nd][32+2*pp+1], pt[nd][64+2*pp+1], x1,y1,z1);
      x0+=tx; y0+=ty; z0+=tz; x1+=tx; y1+=ty; z1+=tz;
      unsigned* d = kv + (size_t)g*48 + pp*3;
      d[0] = pack2(x0,y0); d[1] = pack2(z0,x1); d[2] = pack2(y1,z1);
    }
  }

  // v_v: raw (pre-rotation) points == out_vec; f32 PLANE layout
  pass96(Wvv, stT, cgp, slp, pac);
  __syncthreads();
  if (cgp < 24){
    #pragma unroll
    for (int i=0;i<4;i++){
      #pragma unroll
      for (int c=0;c<4;c++) pt[slp*4+i][cgp*4+c] = pac[i][c];
    }
  }
  __syncthreads();
  #pragma unroll
  for (int r = 0; r < 12; ++r){
    const int idx = tid + r*256;
    const int nd = idx / 96, col = idx - nd*96;
    const int g = node0 + nd;
    if (g < n) vv[(size_t)g*96 + col] = pt[nd][col];
  }
}

// ------------------------------- edge kernel -------------------------------
// 1 thread per CSR edge; bias already staged in logits[p] by k_zfill.
// Only cached gathers remain (q/k working set ~14 MB, L2/L3-resident).

__global__ __launch_bounds__(256) void k_edge(
    const unsigned* __restrict__ si, const unsigned* __restrict__ sj,
    const float* __restrict__ hwts,
    const unsigned* __restrict__ qs, const unsigned* __restrict__ ks,
    const unsigned* __restrict__ qv, const unsigned* __restrict__ kv,
    float* __restrict__ logits, int ne)
{
  const int p = blockIdx.x*256 + threadIdx.x;
  if (p >= ne) return;
  const unsigned i = si[p], j = sj[p];

  const float4 bias = *(const float4*)(logits + (size_t)p*4);

  // ---- scalar attention dot: k_s[i] . q_s[j] per head ----
  const uint4* kr = (const uint4*)(ks + (size_t)i*128);
  const uint4* qr = (const uint4*)(qs + (size_t)j*128);
  float sdot[4];
  #pragma unroll
  for (int h = 0; h < 4; ++h){
    float acc = 0.f;
    #pragma unroll
    for (int c = 0; c < 8; ++c){
      const uint4 a = kr[h*8+c];
      const uint4 b = qr[h*8+c];
      acc += bflo(a.x)*bflo(b.x) + bfhi(a.x)*bfhi(b.x);
      acc += bflo(a.y)*bflo(b.y) + bfhi(a.y)*bfhi(b.y);
      acc += bflo(a.z)*bflo(b.z) + bfhi(a.z)*bfhi(b.z);
      acc += bflo(a.w)*bflo(b.w) + bfhi(a.w)*bfhi(b.w);
    }
    sdot[h] = acc;
  }

  // ---- vector attention: sum_p |q_v[i]-k_v[j]|^2 per head ----
  const uint4* qvr = (const uint4*)(qv + (size_t)i*48);
  const uint4* kvr = (const uint4*)(kv + (size_t)j*48);
  float vsum[4];
  #pragma unroll
  for (int h = 0; h < 4; ++h){
    float acc = 0.f;
    #pragma unroll
    for (int c = 0; c < 3; ++c){
      const uint4 a = qvr[h*3+c];
      const uint4 b = kvr[h*3+c];
      float d;
      d = bflo(a.x)-bflo(b.x); acc += d*d;  d = bfhi(a.x)-bfhi(b.x); acc += d*d;
      d = bflo(a.y)-bflo(b.y); acc += d*d;  d = bfhi(a.y)-bfhi(b.y); acc += d*d;
      d = bflo(a.z)-bflo(b.z); acc += d*d;  d = bfhi(a.z)-bfhi(b.z); acc += d*d;
      d = bflo(a.w)-bflo(b.w); acc += d*d;  d = bfhi(a.w)-bfhi(b.w); acc += d*d;
    }
    vsum[h] = acc;
  }

  float4 lg;
  {
    float l[4];
    const float4 b4 = bias;
    const float bb4[4] = {b4.x, b4.y, b4.z, b4.w};
    #pragma unroll
    for (int h = 0; h < 4; ++h){
      const float hw = log1pf(__expf(hwts[h]));   // softplus
      l[h] = C_SQRT83*sdot[h] + bb4[h] + C_VEC*hw*vsum[h];
    }
    lg.x=l[0]; lg.y=l[1]; lg.z=l[2]; lg.w=l[3];
  }
  *(float4*)(logits + (size_t)p*4) = lg;
}

// ----------------------- wave-per-node softmax + pair -----------------------
// Registers + shuffles only.  Phase 1: lane=edge, per-head max then sum.
// Phase 2: lane=(e4,c) -> 4 edges/iter, acc[h] per lane, butterfly over e4.

__global__ __launch_bounds__(256) void k_soft(
    const float* __restrict__ logits, const unsigned* __restrict__ pz,
    const unsigned* __restrict__ row_off, float* __restrict__ out_pair, int n)
{
  const int node = blockIdx.x*4 + (threadIdx.x >> 6);
  if (node >= n) return;
  const int lane = threadIdx.x & 63;
  const int beg = (int)row_off[node], end = (int)row_off[node+1];

  // ---- phase 1: per-head max and sum (lane-parallel over edges) ----
  float m[4] = {-3.0e38f,-3.0e38f,-3.0e38f,-3.0e38f};
  for (int p = beg + lane; p < end; p += 64){
    const float4 l = *(const float4*)(logits + (size_t)p*4);
    m[0]=fmaxf(m[0],l.x); m[1]=fmaxf(m[1],l.y); m[2]=fmaxf(m[2],l.z); m[3]=fmaxf(m[3],l.w);
  }
  #pragma unroll
  for (int msk = 1; msk < 64; msk <<= 1){
    #pragma unroll
    for (int h=0;h<4;h++) m[h] = fmaxf(m[h], __shfl_xor(m[h], msk));
  }
  float S[4] = {0.f,0.f,0.f,0.f};
  for (int p = beg + lane; p < end; p += 64){
    const float4 l = *(const float4*)(logits + (size_t)p*4);
    S[0]+=__expf(l.x-m[0]); S[1]+=__expf(l.y-m[1]);
    S[2]+=__expf(l.z-m[2]); S[3]+=__expf(l.w-m[3]);
  }
  #pragma unroll
  for (int msk = 1; msk < 64; msk <<= 1){
    #pragma unroll
    for (int h=0;h<4;h++) S[h] += __shfl_xor(S[h], msk);
  }
  float inv[4];
  #pragma unroll
  for (int h=0;h<4;h++) inv[h] = (S[h] > 0.f) ? (1.f/S[h]) : 0.f;

  // ---- phase 2: weighted pair aggregation ----
  const int e4 = lane >> 4, c = lane & 15;
  float acc[4] = {0.f,0.f,0.f,0.f};
  for (int base = beg; base < end; base += 4){
    const int p = base + e4;
    if (p < end){
      const float4 l = *(const float4*)(logits + (size_t)p*4);
      const unsigned u = pz[(size_t)p*8 + (c>>1)];
      const float pzv = (c & 1) ? bfhi(u) : bflo(u);
      acc[0] += __expf(l.x-m[0]) * pzv;
      acc[1] += __expf(l.y-m[1]) * pzv;
      acc[2] += __expf(l.z-m[2]) * pzv;
      acc[3] += __expf(l.w-m[3]) * pzv;
    }
  }
  #pragma unroll
  for (int msk = 16; msk < 64; msk <<= 1){
    #pragma unroll
    for (int h=0;h<4;h++) acc[h] += __shfl_xor(acc[h], msk);
  }
  const int hOut = lane >> 4;          // output layout: [h*16 + c]
  out_pair[(size_t)node*64 + lane] = acc[hOut] * inv[hOut];
}

// --------------------- feats assembly + output GEMM ------------------------

__global__ __launch_bounds__(256) void k_out(
    const float* __restrict__ vs, const float* __restrict__ vv,
    const float* __restrict__ out_pair, const unsigned* __restrict__ row_off,
    const float* __restrict__ quat, const float* __restrict__ trans,
    const float* __restrict__ Wout, const float* __restrict__ bout,
    float* __restrict__ out, int n)
{
  __shared__ float feats[32][448];
  __shared__ int degs[32];
  const int tid = threadIdx.x;
  const int node0 = blockIdx.x*32;

  if (tid < 32){
    const int g = node0 + tid;
    degs[tid] = (g < n) ? (int)(row_off[g+1] - row_off[g]) : 1;
  }
  __syncthreads();

  for (int x = tid; x < 32*256; x += 256){
    const int nd = x >> 8, c = x & 255;
    const int g = node0 + nd;
    feats[nd][c] = (g < n && degs[nd] > 0) ? vs[(size_t)g*256 + c] : 0.f;
  }
  for (int x = tid; x < 32*64; x += 256){
    const int nd = x >> 6, c = x & 63;
    const int g = node0 + nd;
    feats[nd][384 + c] = (g < n) ? out_pair[(size_t)g*64 + c] : 0.f;
  }
  for (int x = tid; x < 32*32; x += 256){
    const int nd = x >> 5, pt = x & 31;
    const int g = node0 + nd;
    float X=0.f, Y=0.f, Z=0.f;
    if (g < n){
      if (degs[nd] > 0){
        X = vv[(size_t)g*96 + pt];
        Y = vv[(size_t)g*96 + 32 + pt];
        Z = vv[(size_t)g*96 + 64 + pt];
      } else {
        const float4 q4 = *(const float4*)(quat + (size_t)g*4);
        const float tx = trans[(size_t)g*3], ty = trans[(size_t)g*3+1], tz = trans[(size_t)g*3+2];
        quat_rot(q4.x, -q4.y, -q4.z, -q4.w, -tx, -ty, -tz, X, Y, Z);
      }
    }
    feats[nd][256 + pt] = X;
    feats[nd][288 + pt] = Y;
    feats[nd][320 + pt] = Z;
    feats[nd][352 + pt] = sqrtf(X*X + Y*Y + Z*Z + 1e-8f);
  }
  __syncthreads();

  const int lane = tid & 63;
  const int wave = tid >> 6;
  float acc[8];
  #pragma unroll
  for (int q8=0;q8<8;q8++) acc[q8]=0.f;

  for (int k0 = 0; k0 < 448; k0 += 4){
    const float w0 = Wout[(size_t)(k0+0)*64 + lane];
    const float w1 = Wout[(size_t)(k0+1)*64 + lane];
    const float w2 = Wout[(size_t)(k0+2)*64 + lane];
    const float w3 = Wout[(size_t)(k0+3)*64 + lane];
    #pragma unroll
    for (int q8 = 0; q8 < 8; ++q8){
      const float4 f = *(const float4*)&feats[wave*8 + q8][k0];
      acc[q8] += f.x*w0 + f.y*w1 + f.z*w2 + f.w*w3;
    }
  }
  const float bo = bout[lane];
  #pragma unroll
  for (int q8 = 0; q8 < 8; ++q8){
    const int g = node0 + wave*8 + q8;
    if (g < n) out[(size_t)g*64 + lane] = acc[q8] + bo;
  }
}

// --------------------------------- launch ----------------------------------

extern "C" void kernel_launch(void* const* d_in, const int* in_sizes, int n_in,
                              void* d_out, int out_size, void* d_ws, size_t ws_size,
                              hipStream_t stream) {
  const float* s     = (const float*)d_in[0];
  const float* z     = (const float*)d_in[1];
  const int*   ei    = (const int*)  d_in[2];
  const float* quat  = (const float*)d_in[3];
  const float* trans = (const float*)d_in[4];
  const float* Wqs   = (const float*)d_in[5];
  const float* Wks   = (const float*)d_in[6];
  const float* Wvs   = (const float*)d_in[7];
  const float* Wqv   = (const float*)d_in[8];
  const float* Wkv   = (const float*)d_in[9];
  const float* Wvv   = (const float*)d_in[10];
  const float* Wb    = (const float*)d_in[11];
  const float* bb    = (const float*)d_in[12];
  const float* Wdz   = (const float*)d_in[13];
  const float* bdz   = (const float*)d_in[14];
  const float* hwts  = (const float*)d_in[15];
  const float* Wout  = (const float*)d_in[16];
  const float* bout  = (const float*)d_in[17];
  float* out = (float*)d_out;

  const int n  = in_sizes[0] / 64;   // 20000
  const int ne = in_sizes[1] / 64;   // 640000

  size_t off = 0;
  char* base = (char*)d_ws;
  auto take = [&](size_t bytes)->char* {
    char* p = base + off;
    off += (bytes + 255) & ~(size_t)255;
    return p;
  };
  unsigned* qs     = (unsigned*)take((size_t)n*512);    // bf16 N x 256
  unsigned* ks     = (unsigned*)take((size_t)n*512);    // bf16 N x 256
  unsigned* qvt    = (unsigned*)take((size_t)n*192);    // bf16 N x 96 (rot + t)
  unsigned* kvt    = (unsigned*)take((size_t)n*192);    // bf16 N x 96 (rot + t)
  float*    vs     = (float*)   take((size_t)n*1024);   // f32  N x 256
  float*    vv     = (float*)   take((size_t)n*384);    // f32  N x 96 (raw, planes)
  float*    logits = (float*)   take((size_t)ne*16);    // f32  E x 4 (CSR order)
  unsigned* pz     = (unsigned*)take((size_t)ne*32);    // bf16 E x 16 (CSR order)
  unsigned* counts = (unsigned*)take((size_t)n*4);
  unsigned* roff   = (unsigned*)take((size_t)(n+1)*4);
  unsigned* rank   = (unsigned*)take((size_t)ne*4);
  unsigned* si     = (unsigned*)take((size_t)ne*4);
  unsigned* sj     = (unsigned*)take((size_t)ne*4);
  float*    opair  = (float*)   take((size_t)n*256);    // f32  N x 64
  (void)ws_size; (void)n_in; (void)out_size;

  const int gbE = (ne + 255) / 256;

  hipMemsetAsync(counts, 0, (size_t)n*4, stream);
  k_count<<<gbE, 256, 0, stream>>>(ei, counts, rank, ne);
  k_scan <<<1,   256, 0, stream>>>(counts, roff, n);
  k_zfill<<<gbE, 256, 0, stream>>>(ei, rank, roff, z, Wb, bb, Wdz, bdz,
                                   si, sj, logits, pz, ne);
  k_proj <<<(n + BN - 1)/BN, 256, 0, stream>>>(s, quat, trans, Wqs, Wks, Wvs, Wqv, Wkv, Wvv,
                                               qs, ks, vs, qvt, kvt, vv, n);
  k_edge <<<gbE, 256, 0, stream>>>(si, sj, hwts, qs, ks, qvt, kvt, logits, ne);
  k_soft <<<(n + 3)/4, 256, 0, stream>>>(logits, pz, roff, opair, n);
  k_out  <<<(n + 31)/32, 256, 0, stream>>>(vs, vv, opair, roff, quat, trans,
                                           Wout, bout, out, n);
}

// Round 3
// 617.044 us; speedup vs baseline: 1.1379x; 1.1379x over previous
//
#include <hip/hip_runtime.h>
#include <stdint.h>

// ---------------------------------------------------------------------------
// InvariantPointAttention, N=20000 nodes, E=640000 edges, H=4, S=64, QK=VD=8
//
// Pipeline (all on `stream`):
//   memset(counts) / k_count / k_scan : CSR build.  k_count stores rank[e]
//       (atomic return).
//   k_proj   : tiled per-node projections (32 nodes/block, transposed LDS
//              s-tile): q_s,k_s (bf16 Nx256), q_v,k_v (rot+trans bf16 Nx96),
//              v_s (f32 Nx256), v_loc (raw points f32 Nx96, PLANE layout).
//   k_zc     : per ORIGINAL edge e, fused z-proj + attention logits:
//              - z staged via LDS (transposed, k-chunked, double-buffered):
//                ALL 256 rows staged per chunk (fixed r2 bug), coalesced
//                16-lines/instr HBM reads, conflict-free LDS reads.
//              - q/k gathers with 4-lane-per-edge split: each load instr
//                touches 16 cache lines, not 64.
//              - one 64-B record/edge {logits f32x4, pz bf16x16} scattered to
//                CSR pos in a single 48-B contiguous store burst.
//   k_soft   : wave-per-node, register/shuffle only softmax + pair aggregation.
//   k_out    : assemble feats[448] per node + feats @ Wout + bout -> out
// ---------------------------------------------------------------------------

#define C_SQRT83  1.6329931618554518f   // sqrt(8/3)
#define C_SQRT13  0.5773502691896258f   // sqrt(1/3)
#define C_VEC    -0.04811252243246881f  // -0.5*sqrt(1/108)

__device__ __forceinline__ unsigned short f2bf(float f){
  unsigned u = __float_as_uint(f);
  u += 0x7fffu + ((u >> 16) & 1u);          // round-to-nearest-even
  return (unsigned short)(u >> 16);
}
__device__ __forceinline__ unsigned pack2(float a, float b){
  return (unsigned)f2bf(a) | ((unsigned)f2bf(b) << 16);
}
__device__ __forceinline__ float bflo(unsigned u){ return __uint_as_float(u << 16); }
__device__ __forceinline__ float bfhi(unsigned u){ return __uint_as_float(u & 0xffff0000u); }

__device__ __forceinline__ void quat_rot(float w, float ux, float uy, float uz,
                                         float vx, float vy, float vz,
                                         float& ox, float& oy, float& oz){
  float cx = uy*vz - uz*vy;
  float cy = uz*vx - ux*vz;
  float cz = ux*vy - uy*vx;
  float dx = uy*cz - uz*cy;
  float dy = uz*cx - ux*cz;
  float dz = ux*cy - uy*cx;
  ox = vx + 2.f*(w*cx + dx);
  oy = vy + 2.f*(w*cy + dy);
  oz = vz + 2.f*(w*cz + dz);
}

// -------------------------------- CSR build --------------------------------

__global__ __launch_bounds__(256) void k_count(const int* __restrict__ ei,
                                               unsigned* __restrict__ counts,
                                               unsigned* __restrict__ rank, int ne){
  int e = blockIdx.x*256 + threadIdx.x;
  if (e >= ne) return;
  rank[e] = atomicAdd(&counts[ei[e]], 1u);
}

__global__ __launch_bounds__(256) void k_scan(const unsigned* __restrict__ counts,
                                              unsigned* __restrict__ row_off, int n){
  __shared__ unsigned part[256];
  int t = threadIdx.x;
  int chunk = (n + 255) >> 8;
  int s0 = t*chunk, s1 = min(s0 + chunk, n);
  unsigned sum = 0;
  for (int k = s0; k < s1; ++k) sum += counts[k];
  part[t] = sum; __syncthreads();
  for (int off = 1; off < 256; off <<= 1){
    unsigned v = (t >= off) ? part[t-off] : 0u;
    __syncthreads();
    part[t] += v;
    __syncthreads();
  }
  unsigned run = (t == 0) ? 0u : part[t-1];
  for (int k = s0; k < s1; ++k){
    row_off[k] = run; run += counts[k];
  }
  if (t == 255) row_off[n] = part[255];
}

// ------------------------------ node projections ----------------------------
// Block = 32 nodes, 256 threads.  s tile TRANSPOSED in LDS: stT[k][node].

#define BN 32

__device__ __forceinline__ void pass256(const float* __restrict__ W,
                                        const float stT[64][40], int cg, int sl,
                                        float acc[8][4]){
  #pragma unroll
  for (int i=0;i<8;i++){ acc[i][0]=0.f; acc[i][1]=0.f; acc[i][2]=0.f; acc[i][3]=0.f; }
  #pragma unroll 4
  for (int k = 0; k < 64; ++k){
    const float4 w  = *(const float4*)(W + (size_t)k*256 + cg*4);
    const float4 n0 = *(const float4*)&stT[k][sl*8];
    const float4 n1 = *(const float4*)&stT[k][sl*8+4];
    acc[0][0]+=n0.x*w.x; acc[0][1]+=n0.x*w.y; acc[0][2]+=n0.x*w.z; acc[0][3]+=n0.x*w.w;
    acc[1][0]+=n0.y*w.x; acc[1][1]+=n0.y*w.y; acc[1][2]+=n0.y*w.z; acc[1][3]+=n0.y*w.w;
    acc[2][0]+=n0.z*w.x; acc[2][1]+=n0.z*w.y; acc[2][2]+=n0.z*w.z; acc[2][3]+=n0.z*w.w;
    acc[3][0]+=n0.w*w.x; acc[3][1]+=n0.w*w.y; acc[3][2]+=n0.w*w.z; acc[3][3]+=n0.w*w.w;
    acc[4][0]+=n1.x*w.x; acc[4][1]+=n1.x*w.y; acc[4][2]+=n1.x*w.z; acc[4][3]+=n1.x*w.w;
    acc[5][0]+=n1.y*w.x; acc[5][1]+=n1.y*w.y; acc[5][2]+=n1.y*w.z; acc[5][3]+=n1.y*w.w;
    acc[6][0]+=n1.z*w.x; acc[6][1]+=n1.z*w.y; acc[6][2]+=n1.z*w.z; acc[6][3]+=n1.z*w.w;
    acc[7][0]+=n1.w*w.x; acc[7][1]+=n1.w*w.y; acc[7][2]+=n1.w*w.z; acc[7][3]+=n1.w*w.w;
  }
}

__device__ __forceinline__ void pass96(const float* __restrict__ W,
                                       const float stT[64][40], int cgp, int slp,
                                       float acc[4][4]){
  #pragma unroll
  for (int i=0;i<4;i++){ acc[i][0]=0.f; acc[i][1]=0.f; acc[i][2]=0.f; acc[i][3]=0.f; }
  if (cgp >= 24) return;
  #pragma unroll 4
  for (int k = 0; k < 64; ++k){
    const float4 w = *(const float4*)(W + (size_t)k*96 + cgp*4);
    const float4 nv = *(const float4*)&stT[k][slp*4];
    acc[0][0]+=nv.x*w.x; acc[0][1]+=nv.x*w.y; acc[0][2]+=nv.x*w.z; acc[0][3]+=nv.x*w.w;
    acc[1][0]+=nv.y*w.x; acc[1][1]+=nv.y*w.y; acc[1][2]+=nv.y*w.z; acc[1][3]+=nv.y*w.w;
    acc[2][0]+=nv.z*w.x; acc[2][1]+=nv.z*w.y; acc[2][2]+=nv.z*w.z; acc[2][3]+=nv.z*w.w;
    acc[3][0]+=nv.w*w.x; acc[3][1]+=nv.w*w.y; acc[3][2]+=nv.w*w.z; acc[3][3]+=nv.w*w.w;
  }
}

__global__ __launch_bounds__(256) void k_proj(
    const float* __restrict__ s, const float* __restrict__ quat, const float* __restrict__ trans,
    const float* __restrict__ Wqs, const float* __restrict__ Wks, const float* __restrict__ Wvs,
    const float* __restrict__ Wqv, const float* __restrict__ Wkv, const float* __restrict__ Wvv,
    unsigned* __restrict__ qs, unsigned* __restrict__ ks, float* __restrict__ vs,
    unsigned* __restrict__ qv, unsigned* __restrict__ kv, float* __restrict__ vv, int n)
{
  __shared__ float stT[64][40];    // transposed s tile (k-major), 16B-aligned cols
  __shared__ float pt[BN][97];     // point staging (x:0..31, y:32..63, z:64..95)
  const int tid = threadIdx.x;
  const int node0 = blockIdx.x * BN;

  #pragma unroll
  for (int r = 0; r < 2; ++r){
    const int idx = tid + r*256;          // float4 index
    const int nd = idx >> 4, c4 = idx & 15;
    const int g = node0 + nd;
    float4 v = make_float4(0.f,0.f,0.f,0.f);
    if (g < n) v = *(const float4*)(s + (size_t)g*64 + c4*4);
    stT[c4*4+0][nd]=v.x; stT[c4*4+1][nd]=v.y; stT[c4*4+2][nd]=v.z; stT[c4*4+3][nd]=v.w;
  }
  __syncthreads();

  const int cg = tid & 63, sl = tid >> 6;
  const int cgp = tid & 31, slp = tid >> 5;
  float acc[8][4];

  pass256(Wqs, stT, cg, sl, acc);
  #pragma unroll
  for (int i=0;i<8;i++){
    const int g = node0 + sl*8 + i;
    if (g < n){
      uint2 u; u.x = pack2(acc[i][0],acc[i][1]); u.y = pack2(acc[i][2],acc[i][3]);
      *(uint2*)(qs + (size_t)g*128 + cg*2) = u;
    }
  }
  pass256(Wks, stT, cg, sl, acc);
  #pragma unroll
  for (int i=0;i<8;i++){
    const int g = node0 + sl*8 + i;
    if (g < n){
      uint2 u; u.x = pack2(acc[i][0],acc[i][1]); u.y = pack2(acc[i][2],acc[i][3]);
      *(uint2*)(ks + (size_t)g*128 + cg*2) = u;
    }
  }
  pass256(Wvs, stT, cg, sl, acc);
  #pragma unroll
  for (int i=0;i<8;i++){
    const int g = node0 + sl*8 + i;
    if (g < n){
      float4 f; f.x=acc[i][0]; f.y=acc[i][1]; f.z=acc[i][2]; f.w=acc[i][3];
      *(float4*)(vs + (size_t)g*256 + cg*4) = f;
    }
  }

  float pac[4][4];

  // q_v: rotate + translate -> bf16
  pass96(Wqv, stT, cgp, slp, pac);
  __syncthreads();
  if (cgp < 24){
    #pragma unroll
    for (int i=0;i<4;i++){
      #pragma unroll
      for (int c=0;c<4;c++) pt[slp*4+i][cgp*4+c] = pac[i][c];
    }
  }
  __syncthreads();
  #pragma unroll
  for (int r = 0; r < 2; ++r){
    const int t2 = tid + r*256;
    const int nd = t2 >> 4, pp = t2 & 15;
    const int g = node0 + nd;
    if (g < n){
      const float4 q4 = *(const float4*)(quat + (size_t)g*4);
      const float tx = trans[(size_t)g*3], ty = trans[(size_t)g*3+1], tz = trans[(size_t)g*3+2];
      float x0,y0,z0,x1,y1,z1;
      quat_rot(q4.x,q4.y,q4.z,q4.w, pt[nd][2*pp],   pt[nd][32+2*pp],   pt[nd][64+2*pp],   x0,y0,z0);
      quat_rot(q4.x,q4.y,q4.z,q4.w, pt[nd][2*pp+1], pt[nd][32+2*pp+1], pt[nd][64+2*pp+1], x1,y1,z1);
      x0+=tx; y0+=ty; z0+=tz; x1+=tx; y1+=ty; z1+=tz;
      unsigned* d = qv + (size_t)g*48 + pp*3;
      d[0] = pack2(x0,y0); d[1] = pack2(z0,x1); d[2] = pack2(y1,z1);
    }
  }

  // k_v: rotate + translate -> bf16
  pass96(Wkv, stT, cgp, slp, pac);
  __syncthreads();
  if (cgp < 24){
    #pragma unroll
    for (int i=0;i<4;i++){
      #pragma unroll
      for (int c=0;c<4;c++) pt[slp*4+i][cgp*4+c] = pac[i][c];
    }
  }
  __syncthreads();
  #pragma unroll
  for (int r = 0; r < 2; ++r){
    const int t2 = tid + r*256;
    const int nd = t2 >> 4, pp = t2 & 15;
    const int g = node0 + nd;
    if (g < n){
      const float4 q4 = *(const float4*)(quat + (size_t)g*4);
      const float tx = trans[(size_t)g*3], ty = trans[(size_t)g*3+1], tz = trans[(size_t)g*3+2];
      float x0,y0,z0,x1,y1,z1;
      quat_rot(q4.x,q4.y,q4.z,q4.w, pt[nd][2*pp],   pt[nd][32+2*pp],   pt[nd][64+2*pp],   x0,y0,z0);
      quat_rot(q4.x,q4.y,q4.z,q4.w, pt[nd][2*pp+1], pt[nd][32+2*pp+1], pt[nd][64+2*pp+1], x1,y1,z1);
      x0+=tx; y0+=ty; z0+=tz; x1+=tx; y1+=ty; z1+=tz;
      unsigned* d = kv + (size_t)g*48 + pp*3;
      d[0] = pack2(x0,y0); d[1] = pack2(z0,x1); d[2] = pack2(y1,z1);
    }
  }

  // v_v: raw (pre-rotation) points == out_vec; f32 PLANE layout
  pass96(Wvv, stT, cgp, slp, pac);
  __syncthreads();
  if (cgp < 24){
    #pragma unroll
    for (int i=0;i<4;i++){
      #pragma unroll
      for (int c=0;c<4;c++) pt[slp*4+i][cgp*4+c] = pac[i][c];
    }
  }
  __syncthreads();
  #pragma unroll
  for (int r = 0; r < 12; ++r){
    const int idx = tid + r*256;
    const int nd = idx / 96, col = idx - nd*96;
    const int g = node0 + nd;
    if (g < n) vv[(size_t)g*96 + col] = pt[nd][col];
  }
}

// ---------------- fused z-proj + edge logits (k_zc) ------------------------
// Block = 256 threads = 256 original-order edges.
// Record per edge at CSR pos: 16 uints = {logits f32 x4 | pz bf16 x16 | pad}.

__global__ __launch_bounds__(256) void k_zc(
    const int* __restrict__ ei, const unsigned* __restrict__ rank,
    const unsigned* __restrict__ roff, const float* __restrict__ z,
    const float* __restrict__ Wb,  const float* __restrict__ bb,
    const float* __restrict__ Wdz, const float* __restrict__ bdz,
    const float* __restrict__ hwts,
    const unsigned* __restrict__ qs, const unsigned* __restrict__ ks,
    const unsigned* __restrict__ qv, const unsigned* __restrict__ kv,
    unsigned* __restrict__ rec, int ne)
{
  __shared__ float zT[2][16][258];   // k-chunked transposed z tile, dbuf (pad 258)
  const int tid = threadIdx.x;
  const int E0  = blockIdx.x * 256;
  const int e   = E0 + tid;
  const bool full = (E0 + 256 <= ne);

  int i = 0, j = 0; unsigned pos = 0;
  if (e < ne){
    i = ei[e]; j = ei[ne + e];
    pos = roff[i] + rank[e];
  }

  // folded softplus head weights (include C_VEC)
  const float hw0 = C_VEC * log1pf(__expf(hwts[0]));
  const float hw1 = C_VEC * log1pf(__expf(hwts[1]));
  const float hw2 = C_VEC * log1pf(__expf(hwts[2]));
  const float hw3 = C_VEC * log1pf(__expf(hwts[3]));

  // ---------------- z projection ----------------
  float b4[4] = {0.f,0.f,0.f,0.f};
  float pacc[16];
  #pragma unroll
  for (int c=0;c<16;c++) pacc[c]=0.f;

  if (full){
    // stage chunk 0 into buf 0: ALL 256 rows x 16 k, coalesced (16 lines/instr)
    #pragma unroll
    for (int q = 0; q < 4; ++q){
      const int idx = tid + q*256;           // 0..1023
      const int row = idx >> 2, f4 = idx & 3;
      const float4 v = *(const float4*)(z + (size_t)(E0+row)*64 + f4*4);
      zT[0][f4*4+0][row]=v.x; zT[0][f4*4+1][row]=v.y;
      zT[0][f4*4+2][row]=v.z; zT[0][f4*4+3][row]=v.w;
    }
    __syncthreads();
    #pragma unroll
    for (int c = 0; c < 4; ++c){
      if (c < 3){
        const int nb = (c+1)&1;
        #pragma unroll
        for (int q = 0; q < 4; ++q){
          const int idx = tid + q*256;
          const int row = idx >> 2, f4 = idx & 3;
          const float4 v = *(const float4*)(z + (size_t)(E0+row)*64 + (c+1)*16 + f4*4);
          zT[nb][f4*4+0][row]=v.x; zT[nb][f4*4+1][row]=v.y;
          zT[nb][f4*4+2][row]=v.z; zT[nb][f4*4+3][row]=v.w;
        }
      }
      const int kb = c*16, buf = c&1;
      #pragma unroll
      for (int kk = 0; kk < 16; ++kk){
        const float zk = zT[buf][kk][tid];
        const int k = kb + kk;
        const float4 wb = *(const float4*)(Wb + k*4);
        b4[0]+=zk*wb.x; b4[1]+=zk*wb.y; b4[2]+=zk*wb.z; b4[3]+=zk*wb.w;
        const float* wd = Wdz + k*16;
        const float4 w0=*(const float4*)(wd),   w1=*(const float4*)(wd+4),
                     w2=*(const float4*)(wd+8), w3=*(const float4*)(wd+12);
        pacc[ 0]+=zk*w0.x; pacc[ 1]+=zk*w0.y; pacc[ 2]+=zk*w0.z; pacc[ 3]+=zk*w0.w;
        pacc[ 4]+=zk*w1.x; pacc[ 5]+=zk*w1.y; pacc[ 6]+=zk*w1.z; pacc[ 7]+=zk*w1.w;
        pacc[ 8]+=zk*w2.x; pacc[ 9]+=zk*w2.y; pacc[10]+=zk*w2.z; pacc[11]+=zk*w2.w;
        pacc[12]+=zk*w3.x; pacc[13]+=zk*w3.y; pacc[14]+=zk*w3.z; pacc[15]+=zk*w3.w;
      }
      __syncthreads();
    }
  } else if (e < ne){
    const float* zr = z + (size_t)e*64;
    for (int k4 = 0; k4 < 16; ++k4){
      const float4 zv = *(const float4*)(zr + 4*k4);
      #pragma unroll
      for (int kk = 0; kk < 4; ++kk){
        const int k = 4*k4 + kk;
        const float zk = (kk==0)?zv.x:((kk==1)?zv.y:((kk==2)?zv.z:zv.w));
        const float4 wb = *(const float4*)(Wb + k*4);
        b4[0]+=zk*wb.x; b4[1]+=zk*wb.y; b4[2]+=zk*wb.z; b4[3]+=zk*wb.w;
        const float* wd = Wdz + k*16;
        const float4 w0=*(const float4*)(wd),   w1=*(const float4*)(wd+4),
                     w2=*(const float4*)(wd+8), w3=*(const float4*)(wd+12);
        pacc[ 0]+=zk*w0.x; pacc[ 1]+=zk*w0.y; pacc[ 2]+=zk*w0.z; pacc[ 3]+=zk*w0.w;
        pacc[ 4]+=zk*w1.x; pacc[ 5]+=zk*w1.y; pacc[ 6]+=zk*w1.z; pacc[ 7]+=zk*w1.w;
        pacc[ 8]+=zk*w2.x; pacc[ 9]+=zk*w2.y; pacc[10]+=zk*w2.z; pacc[11]+=zk*w2.w;
        pacc[12]+=zk*w3.x; pacc[13]+=zk*w3.y; pacc[14]+=zk*w3.z; pacc[15]+=zk*w3.w;
      }
    }
  }

  // pack pz + fold bias
  uint4 u0, u1;
  float bl0=0.f, bl1=0.f, bl2=0.f, bl3=0.f;
  if (e < ne){
    #pragma unroll
    for (int c=0;c<16;c++) pacc[c] += bdz[c];
    u0.x=pack2(pacc[0],pacc[1]);   u0.y=pack2(pacc[2],pacc[3]);
    u0.z=pack2(pacc[4],pacc[5]);   u0.w=pack2(pacc[6],pacc[7]);
    u1.x=pack2(pacc[8],pacc[9]);   u1.y=pack2(pacc[10],pacc[11]);
    u1.z=pack2(pacc[12],pacc[13]); u1.w=pack2(pacc[14],pacc[15]);
    bl0 = C_SQRT13*(b4[0] + bb[0]);
    bl1 = C_SQRT13*(b4[1] + bb[1]);
    bl2 = C_SQRT13*(b4[2] + bb[2]);
    bl3 = C_SQRT13*(b4[3] + bb[3]);
  } else {
    u0 = make_uint4(0,0,0,0); u1 = make_uint4(0,0,0,0);
  }

  // ---------------- attention terms ----------------
  if (full){
    // 4-lane-per-edge split: group g = lane>>2 handles edge el = sb*16+g of
    // its own wave; lane c = lane&3 reads 16-B slices (4 lanes cover a 64-B
    // line -> 16 lines/instruction).
    const int l = tid & 63;
    const int c = l & 3, g = l >> 2;
    #pragma unroll
    for (int sb = 0; sb < 4; ++sb){
      const int el = sb*16 + g;
      const int ie = __shfl(i, el, 64);
      const int je = __shfl(j, el, 64);

      // scalar dot (heads from k-slice index, compile-time per it)
      const uint4* kr = (const uint4*)ks + (size_t)ie*32;
      const uint4* qr = (const uint4*)qs + (size_t)je*32;
      float s0=0.f, s1=0.f, s2=0.f, s3=0.f;
      #pragma unroll
      for (int it = 0; it < 8; ++it){
        const uint4 a = kr[it*4 + c];
        const uint4 b = qr[it*4 + c];
        float d;
        d  = bflo(a.x)*bflo(b.x) + bfhi(a.x)*bfhi(b.x);
        d += bflo(a.y)*bflo(b.y) + bfhi(a.y)*bfhi(b.y);
        d += bflo(a.z)*bflo(b.z) + bfhi(a.z)*bfhi(b.z);
        d += bflo(a.w)*bflo(b.w) + bfhi(a.w)*bfhi(b.w);
        if      (it < 2) s0 += d;
        else if (it < 4) s1 += d;
        else if (it < 6) s2 += d;
        else             s3 += d;
      }

      // vector attention (head = uint4-idx/3; uint4-idx = chunk*4+c)
      const uint4* qvr = (const uint4*)qv + (size_t)ie*12;
      const uint4* kvr = (const uint4*)kv + (size_t)je*12;
      float v0=0.f, v1=0.f, v2=0.f, v3=0.f;
      {
        const uint4 a = qvr[c], b = kvr[c];
        float d, t;
        t = bflo(a.x)-bflo(b.x); d  = t*t;  t = bfhi(a.x)-bfhi(b.x); d += t*t;
        t = bflo(a.y)-bflo(b.y); d += t*t;  t = bfhi(a.y)-bfhi(b.y); d += t*t;
        t = bflo(a.z)-bflo(b.z); d += t*t;  t = bfhi(a.z)-bfhi(b.z); d += t*t;
        t = bflo(a.w)-bflo(b.w); d += t*t;  t = bfhi(a.w)-bfhi(b.w); d += t*t;
        if (c < 3) v0 += d; else v1 += d;
      }
      {
        const uint4 a = qvr[4+c], b = kvr[4+c];
        float d, t;
        t = bflo(a.x)-bflo(b.x); d  = t*t;  t = bfhi(a.x)-bfhi(b.x); d += t*t;
        t = bflo(a.y)-bflo(b.y); d += t*t;  t = bfhi(a.y)-bfhi(b.y); d += t*t;
        t = bflo(a.z)-bflo(b.z); d += t*t;  t = bfhi(a.z)-bfhi(b.z); d += t*t;
        t = bflo(a.w)-bflo(b.w); d += t*t;  t = bfhi(a.w)-bfhi(b.w); d += t*t;
        if (c < 2) v1 += d; else v2 += d;
      }
      {
        const uint4 a = qvr[8+c], b = kvr[8+c];
        float d, t;
        t = bflo(a.x)-bflo(b.x); d  = t*t;  t = bfhi(a.x)-bfhi(b.x); d += t*t;
        t = bflo(a.y)-bflo(b.y); d += t*t;  t = bfhi(a.y)-bfhi(b.y); d += t*t;
        t = bflo(a.z)-bflo(b.z); d += t*t;  t = bfhi(a.z)-bfhi(b.z); d += t*t;
        t = bflo(a.w)-bflo(b.w); d += t*t;  t = bfhi(a.w)-bfhi(b.w); d += t*t;
        if (c < 1) v2 += d; else v3 += d;
      }

      // fold per-head partial logit, reduce across the 4 lanes of the group
      float p0 = C_SQRT83*s0 + hw0*v0;
      float p1 = C_SQRT83*s1 + hw1*v1;
      float p2 = C_SQRT83*s2 + hw2*v2;
      float p3 = C_SQRT83*s3 + hw3*v3;
      #pragma unroll
      for (int msk = 1; msk < 4; msk <<= 1){
        p0 += __shfl_xor(p0, msk, 64);
        p1 += __shfl_xor(p1, msk, 64);
        p2 += __shfl_xor(p2, msk, 64);
        p3 += __shfl_xor(p3, msk, 64);
      }
      const float pc = (c==0)?p0:((c==1)?p1:((c==2)?p2:p3));

      // route the 4 head-logits back to the owning lane (owners: l>>4 == sb)
      const int srcbase = (l & 15) << 2;
      const float q0 = __shfl(pc, srcbase+0, 64);
      const float q1 = __shfl(pc, srcbase+1, 64);
      const float q2 = __shfl(pc, srcbase+2, 64);
      const float q3 = __shfl(pc, srcbase+3, 64);
      if ((l >> 4) == sb){
        uint4* d = (uint4*)rec + (size_t)pos*4;
        float4 lg; lg.x = q0 + bl0; lg.y = q1 + bl1; lg.z = q2 + bl2; lg.w = q3 + bl3;
        d[0] = *(uint4*)&lg;
        d[1] = u0;
        d[2] = u1;
      }
    }
  } else if (e < ne){
    // tail block: per-thread gather (never hit when ne % 256 == 0)
    const uint4* kr = (const uint4*)ks + (size_t)i*32;
    const uint4* qr = (const uint4*)qs + (size_t)j*32;
    float sdot[4];
    #pragma unroll
    for (int h = 0; h < 4; ++h){
      float acc = 0.f;
      #pragma unroll
      for (int cc = 0; cc < 8; ++cc){
        const uint4 a = kr[h*8+cc];
        const uint4 b = qr[h*8+cc];
        acc += bflo(a.x)*bflo(b.x) + bfhi(a.x)*bfhi(b.x);
        acc += bflo(a.y)*bflo(b.y) + bfhi(a.y)*bfhi(b.y);
        acc += bflo(a.z)*bflo(b.z) + bfhi(a.z)*bfhi(b.z);
        acc += bflo(a.w)*bflo(b.w) + bfhi(a.w)*bfhi(b.w);
      }
      sdot[h] = acc;
    }
    const uint4* qvr = (const uint4*)qv + (size_t)i*12;
    const uint4* kvr = (const uint4*)kv + (size_t)j*12;
    float vsum[4];
    #pragma unroll
    for (int h = 0; h < 4; ++h){
      float acc = 0.f;
      #pragma unroll
      for (int cc = 0; cc < 3; ++cc){
        const uint4 a = qvr[h*3+cc];
        const uint4 b = kvr[h*3+cc];
        float d;
        d = bflo(a.x)-bflo(b.x); acc += d*d;  d = bfhi(a.x)-bfhi(b.x); acc += d*d;
        d = bflo(a.y)-bflo(b.y); acc += d*d;  d = bfhi(a.y)-bfhi(b.y); acc += d*d;
        d = bflo(a.z)-bflo(b.z); acc += d*d;  d = bfhi(a.z)-bfhi(b.z); acc += d*d;
        d = bflo(a.w)-bflo(b.w); acc += d*d;  d = bfhi(a.w)-bfhi(b.w); acc += d*d;
      }
      vsum[h] = acc;
    }
    float4 lg;
    lg.x = C_SQRT83*sdot[0] + bl0 + hw0*vsum[0];
    lg.y = C_SQRT83*sdot[1] + bl1 + hw1*vsum[1];
    lg.z = C_SQRT83*sdot[2] + bl2 + hw2*vsum[2];
    lg.w = C_SQRT83*sdot[3] + bl3 + hw3*vsum[3];
    uint4* d = (uint4*)rec + (size_t)pos*4;
    d[0] = *(uint4*)&lg;
    d[1] = u0;
    d[2] = u1;
  }
}

// ----------------------- wave-per-node softmax + pair -----------------------
// rec layout per edge: uint[16] = {logits f32 x4, pz bf16 x16 (8 uints), pad}

__global__ __launch_bounds__(256) void k_soft(
    const unsigned* __restrict__ rec,
    const unsigned* __restrict__ row_off, float* __restrict__ out_pair, int n)
{
  const int node = blockIdx.x*4 + (threadIdx.x >> 6);
  if (node >= n) return;
  const int lane = threadIdx.x & 63;
  const int beg = (int)row_off[node], end = (int)row_off[node+1];
  const float* recf = (const float*)rec;

  // ---- phase 1: per-head max and sum (lane-parallel over edges) ----
  float m[4] = {-3.0e38f,-3.0e38f,-3.0e38f,-3.0e38f};
  for (int p = beg + lane; p < end; p += 64){
    const float4 l = *(const float4*)(recf + (size_t)p*16);
    m[0]=fmaxf(m[0],l.x); m[1]=fmaxf(m[1],l.y); m[2]=fmaxf(m[2],l.z); m[3]=fmaxf(m[3],l.w);
  }
  #pragma unroll
  for (int msk = 1; msk < 64; msk <<= 1){
    #pragma unroll
    for (int h=0;h<4;h++) m[h] = fmaxf(m[h], __shfl_xor(m[h], msk));
  }
  float S[4] = {0.f,0.f,0.f,0.f};
  for (int p = beg + lane; p < end; p += 64){
    const float4 l = *(const float4*)(recf + (size_t)p*16);
    S[0]+=__expf(l.x-m[0]); S[1]+=__expf(l.y-m[1]);
    S[2]+=__expf(l.z-m[2]); S[3]+=__expf(l.w-m[3]);
  }
  #pragma unroll
  for (int msk = 1; msk < 64; msk <<= 1){
    #pragma unroll
    for (int h=0;h<4;h++) S[h] += __shfl_xor(S[h], msk);
  }
  float inv[4];
  #pragma unroll
  for (int h=0;h<4;h++) inv[h] = (S[h] > 0.f) ? (1.f/S[h]) : 0.f;

  // ---- phase 2: weighted pair aggregation ----
  const int e4 = lane >> 4, c = lane & 15;
  float acc[4] = {0.f,0.f,0.f,0.f};
  for (int base = beg; base < end; base += 4){
    const int p = base + e4;
    if (p < end){
      const float4 l = *(const float4*)(recf + (size_t)p*16);
      const unsigned u = rec[(size_t)p*16 + 4 + (c>>1)];
      const float pzv = (c & 1) ? bfhi(u) : bflo(u);
      acc[0] += __expf(l.x-m[0]) * pzv;
      acc[1] += __expf(l.y-m[1]) * pzv;
      acc[2] += __expf(l.z-m[2]) * pzv;
      acc[3] += __expf(l.w-m[3]) * pzv;
    }
  }
  #pragma unroll
  for (int msk = 16; msk < 64; msk <<= 1){
    #pragma unroll
    for (int h=0;h<4;h++) acc[h] += __shfl_xor(acc[h], msk);
  }
  const int hOut = lane >> 4;          // output layout: [h*16 + c]
  out_pair[(size_t)node*64 + lane] = acc[hOut] * inv[hOut];
}

// --------------------- feats assembly + output GEMM ------------------------

__global__ __launch_bounds__(256) void k_out(
    const float* __restrict__ vs, const float* __restrict__ vv,
    const float* __restrict__ out_pair, const unsigned* __restrict__ row_off,
    const float* __restrict__ quat, const float* __restrict__ trans,
    const float* __restrict__ Wout, const float* __restrict__ bout,
    float* __restrict__ out, int n)
{
  __shared__ float feats[32][448];
  __shared__ int degs[32];
  const int tid = threadIdx.x;
  const int node0 = blockIdx.x*32;

  if (tid < 32){
    const int g = node0 + tid;
    degs[tid] = (g < n) ? (int)(row_off[g+1] - row_off[g]) : 1;
  }
  __syncthreads();

  for (int x = tid; x < 32*256; x += 256){
    const int nd = x >> 8, c = x & 255;
    const int g = node0 + nd;
    feats[nd][c] = (g < n && degs[nd] > 0) ? vs[(size_t)g*256 + c] : 0.f;
  }
  for (int x = tid; x < 32*64; x += 256){
    const int nd = x >> 6, c = x & 63;
    const int g = node0 + nd;
    feats[nd][384 + c] = (g < n) ? out_pair[(size_t)g*64 + c] : 0.f;
  }
  for (int x = tid; x < 32*32; x += 256){
    const int nd = x >> 5, pt = x & 31;
    const int g = node0 + nd;
    float X=0.f, Y=0.f, Z=0.f;
    if (g < n){
      if (degs[nd] > 0){
        X = vv[(size_t)g*96 + pt];
        Y = vv[(size_t)g*96 + 32 + pt];
        Z = vv[(size_t)g*96 + 64 + pt];
      } else {
        const float4 q4 = *(const float4*)(quat + (size_t)g*4);
        const float tx = trans[(size_t)g*3], ty = trans[(size_t)g*3+1], tz = trans[(size_t)g*3+2];
        quat_rot(q4.x, -q4.y, -q4.z, -q4.w, -tx, -ty, -tz, X, Y, Z);
      }
    }
    feats[nd][256 + pt] = X;
    feats[nd][288 + pt] = Y;
    feats[nd][320 + pt] = Z;
    feats[nd][352 + pt] = sqrtf(X*X + Y*Y + Z*Z + 1e-8f);
  }
  __syncthreads();

  const int lane = tid & 63;
  const int wave = tid >> 6;
  float acc[8];
  #pragma unroll
  for (int q8=0;q8<8;q8++) acc[q8]=0.f;

  for (int k0 = 0; k0 < 448; k0 += 4){
    const float w0 = Wout[(size_t)(k0+0)*64 + lane];
    const float w1 = Wout[(size_t)(k0+1)*64 + lane];
    const float w2 = Wout[(size_t)(k0+2)*64 + lane];
    const float w3 = Wout[(size_t)(k0+3)*64 + lane];
    #pragma unroll
    for (int q8 = 0; q8 < 8; ++q8){
      const float4 f = *(const float4*)&feats[wave*8 + q8][k0];
      acc[q8] += f.x*w0 + f.y*w1 + f.z*w2 + f.w*w3;
    }
  }
  const float bo = bout[lane];
  #pragma unroll
  for (int q8 = 0; q8 < 8; ++q8){
    const int g = node0 + wave*8 + q8;
    if (g < n) out[(size_t)g*64 + lane] = acc[q8] + bo;
  }
}

// --------------------------------- launch ----------------------------------

extern "C" void kernel_launch(void* const* d_in, const int* in_sizes, int n_in,
                              void* d_out, int out_size, void* d_ws, size_t ws_size,
                              hipStream_t stream) {
  const float* s     = (const float*)d_in[0];
  const float* z     = (const float*)d_in[1];
  const int*   ei    = (const int*)  d_in[2];
  const float* quat  = (const float*)d_in[3];
  const float* trans = (const float*)d_in[4];
  const float* Wqs   = (const float*)d_in[5];
  const float* Wks   = (const float*)d_in[6];
  const float* Wvs   = (const float*)d_in[7];
  const float* Wqv   = (const float*)d_in[8];
  const float* Wkv   = (const float*)d_in[9];
  const float* Wvv   = (const float*)d_in[10];
  const float* Wb    = (const float*)d_in[11];
  const float* bb    = (const float*)d_in[12];
  const float* Wdz   = (const float*)d_in[13];
  const float* bdz   = (const float*)d_in[14];
  const float* hwts  = (const float*)d_in[15];
  const float* Wout  = (const float*)d_in[16];
  const float* bout  = (const float*)d_in[17];
  float* out = (float*)d_out;

  const int n  = in_sizes[0] / 64;   // 20000
  const int ne = in_sizes[1] / 64;   // 640000

  size_t off = 0;
  char* base = (char*)d_ws;
  auto take = [&](size_t bytes)->char* {
    char* p = base + off;
    off += (bytes + 255) & ~(size_t)255;
    return p;
  };
  unsigned* qs     = (unsigned*)take((size_t)n*512);    // bf16 N x 256
  unsigned* ks     = (unsigned*)take((size_t)n*512);    // bf16 N x 256
  unsigned* qvt    = (unsigned*)take((size_t)n*192);    // bf16 N x 96 (rot + t)
  unsigned* kvt    = (unsigned*)take((size_t)n*192);    // bf16 N x 96 (rot + t)
  float*    vs     = (float*)   take((size_t)n*1024);   // f32  N x 256
  float*    vv     = (float*)   take((size_t)n*384);    // f32  N x 96 (raw, planes)
  unsigned* rec    = (unsigned*)take((size_t)ne*64);    // 64-B record per edge
  unsigned* counts = (unsigned*)take((size_t)n*4);
  unsigned* roff   = (unsigned*)take((size_t)(n+1)*4);
  unsigned* rank   = (unsigned*)take((size_t)ne*4);
  float*    opair  = (float*)   take((size_t)n*256);    // f32  N x 64
  (void)ws_size; (void)n_in; (void)out_size;

  const int gbE = (ne + 255) / 256;

  hipMemsetAsync(counts, 0, (size_t)n*4, stream);
  k_count<<<gbE, 256, 0, stream>>>(ei, counts, rank, ne);
  k_scan <<<1,   256, 0, stream>>>(counts, roff, n);
  k_proj <<<(n + BN - 1)/BN, 256, 0, stream>>>(s, quat, trans, Wqs, Wks, Wvs, Wqv, Wkv, Wvv,
                                               qs, ks, vs, qvt, kvt, vv, n);
  k_zc   <<<gbE, 256, 0, stream>>>(ei, rank, roff, z, Wb, bb, Wdz, bdz, hwts,
                                   qs, ks, qvt, kvt, rec, ne);
  k_soft <<<(n + 3)/4, 256, 0, stream>>>(rec, roff, opair, n);
  k_out  <<<(n + 31)/32, 256, 0, stream>>>(vs, vv, opair, roff, quat, trans,
                                           Wout, bout, out, n);
}

// Round 4
// 598.325 us; speedup vs baseline: 1.1735x; 1.0313x over previous
//
#include <hip/hip_runtime.h>
#include <stdint.h>

// ---------------------------------------------------------------------------
// InvariantPointAttention, N=20000 nodes, E=640000 edges, H=4, S=64, QK=VD=8
//
// Pipeline (all on `stream`):
//   memset(counts) / k_count / k_scan : CSR build.  k_count stores rank[e]
//       (atomic return).
//   k_proj   : tiled per-node projections (32 nodes/block, transposed LDS
//              s-tile): q_s,k_s (bf16 Nx256), q_v,k_v (rot+trans bf16 Nx96),
//              v_s (f32 Nx256), v_loc (raw points f32 Nx96, PLANE layout).
//   k_zf     : per ORIGINAL edge e (coalesced z stream via single-buffered
//              16.5 KB LDS transpose tile): z@Wb -> bias, z@Wdz -> pz;
//              scatters 64-B record {bias f32x4, pz bf16x16, i, j} to CSR pos.
//   k_edge   : per CSR edge (i-side locality: consecutive edges share i ->
//              ks[i]/qv[i] are L1 hits; only qs[j]/kv[j] random).  4-lane-per-
//              edge split gathers (16 lines/instr).  logits = bias + attn
//              terms, written back into the record.  No LDS -> high occupancy.
//   k_soft   : wave-per-node, register/shuffle only softmax + pair aggregation.
//   k_out    : assemble feats[448] per node + feats @ Wout + bout -> out
// ---------------------------------------------------------------------------

#define C_SQRT83  1.6329931618554518f   // sqrt(8/3)
#define C_SQRT13  0.5773502691896258f   // sqrt(1/3)
#define C_VEC    -0.04811252243246881f  // -0.5*sqrt(1/108)

__device__ __forceinline__ unsigned short f2bf(float f){
  unsigned u = __float_as_uint(f);
  u += 0x7fffu + ((u >> 16) & 1u);          // round-to-nearest-even
  return (unsigned short)(u >> 16);
}
__device__ __forceinline__ unsigned pack2(float a, float b){
  return (unsigned)f2bf(a) | ((unsigned)f2bf(b) << 16);
}
__device__ __forceinline__ float bflo(unsigned u){ return __uint_as_float(u << 16); }
__device__ __forceinline__ float bfhi(unsigned u){ return __uint_as_float(u & 0xffff0000u); }

__device__ __forceinline__ void quat_rot(float w, float ux, float uy, float uz,
                                         float vx, float vy, float vz,
                                         float& ox, float& oy, float& oz){
  float cx = uy*vz - uz*vy;
  float cy = uz*vx - ux*vz;
  float cz = ux*vy - uy*vx;
  float dx = uy*cz - uz*cy;
  float dy = uz*cx - ux*cz;
  float dz = ux*cy - uy*cx;
  ox = vx + 2.f*(w*cx + dx);
  oy = vy + 2.f*(w*cy + dy);
  oz = vz + 2.f*(w*cz + dz);
}

// -------------------------------- CSR build --------------------------------

__global__ __launch_bounds__(256) void k_count(const int* __restrict__ ei,
                                               unsigned* __restrict__ counts,
                                               unsigned* __restrict__ rank, int ne){
  int e = blockIdx.x*256 + threadIdx.x;
  if (e >= ne) return;
  rank[e] = atomicAdd(&counts[ei[e]], 1u);
}

__global__ __launch_bounds__(256) void k_scan(const unsigned* __restrict__ counts,
                                              unsigned* __restrict__ row_off, int n){
  __shared__ unsigned part[256];
  int t = threadIdx.x;
  int chunk = (n + 255) >> 8;
  int s0 = t*chunk, s1 = min(s0 + chunk, n);
  unsigned sum = 0;
  for (int k = s0; k < s1; ++k) sum += counts[k];
  part[t] = sum; __syncthreads();
  for (int off = 1; off < 256; off <<= 1){
    unsigned v = (t >= off) ? part[t-off] : 0u;
    __syncthreads();
    part[t] += v;
    __syncthreads();
  }
  unsigned run = (t == 0) ? 0u : part[t-1];
  for (int k = s0; k < s1; ++k){
    row_off[k] = run; run += counts[k];
  }
  if (t == 255) row_off[n] = part[255];
}

// ------------------------------ node projections ----------------------------
// Block = 32 nodes, 256 threads.  s tile TRANSPOSED in LDS: stT[k][node].

#define BN 32

__device__ __forceinline__ void pass256(const float* __restrict__ W,
                                        const float stT[64][40], int cg, int sl,
                                        float acc[8][4]){
  #pragma unroll
  for (int i=0;i<8;i++){ acc[i][0]=0.f; acc[i][1]=0.f; acc[i][2]=0.f; acc[i][3]=0.f; }
  #pragma unroll 4
  for (int k = 0; k < 64; ++k){
    const float4 w  = *(const float4*)(W + (size_t)k*256 + cg*4);
    const float4 n0 = *(const float4*)&stT[k][sl*8];
    const float4 n1 = *(const float4*)&stT[k][sl*8+4];
    acc[0][0]+=n0.x*w.x; acc[0][1]+=n0.x*w.y; acc[0][2]+=n0.x*w.z; acc[0][3]+=n0.x*w.w;
    acc[1][0]+=n0.y*w.x; acc[1][1]+=n0.y*w.y; acc[1][2]+=n0.y*w.z; acc[1][3]+=n0.y*w.w;
    acc[2][0]+=n0.z*w.x; acc[2][1]+=n0.z*w.y; acc[2][2]+=n0.z*w.z; acc[2][3]+=n0.z*w.w;
    acc[3][0]+=n0.w*w.x; acc[3][1]+=n0.w*w.y; acc[3][2]+=n0.w*w.z; acc[3][3]+=n0.w*w.w;
    acc[4][0]+=n1.x*w.x; acc[4][1]+=n1.x*w.y; acc[4][2]+=n1.x*w.z; acc[4][3]+=n1.x*w.w;
    acc[5][0]+=n1.y*w.x; acc[5][1]+=n1.y*w.y; acc[5][2]+=n1.y*w.z; acc[5][3]+=n1.y*w.w;
    acc[6][0]+=n1.z*w.x; acc[6][1]+=n1.z*w.y; acc[6][2]+=n1.z*w.z; acc[6][3]+=n1.z*w.w;
    acc[7][0]+=n1.w*w.x; acc[7][1]+=n1.w*w.y; acc[7][2]+=n1.w*w.z; acc[7][3]+=n1.w*w.w;
  }
}

__device__ __forceinline__ void pass96(const float* __restrict__ W,
                                       const float stT[64][40], int cgp, int slp,
                                       float acc[4][4]){
  #pragma unroll
  for (int i=0;i<4;i++){ acc[i][0]=0.f; acc[i][1]=0.f; acc[i][2]=0.f; acc[i][3]=0.f; }
  if (cgp >= 24) return;
  #pragma unroll 4
  for (int k = 0; k < 64; ++k){
    const float4 w = *(const float4*)(W + (size_t)k*96 + cgp*4);
    const float4 nv = *(const float4*)&stT[k][slp*4];
    acc[0][0]+=nv.x*w.x; acc[0][1]+=nv.x*w.y; acc[0][2]+=nv.x*w.z; acc[0][3]+=nv.x*w.w;
    acc[1][0]+=nv.y*w.x; acc[1][1]+=nv.y*w.y; acc[1][2]+=nv.y*w.z; acc[1][3]+=nv.y*w.w;
    acc[2][0]+=nv.z*w.x; acc[2][1]+=nv.z*w.y; acc[2][2]+=nv.z*w.z; acc[2][3]+=nv.z*w.w;
    acc[3][0]+=nv.w*w.x; acc[3][1]+=nv.w*w.y; acc[3][2]+=nv.w*w.z; acc[3][3]+=nv.w*w.w;
  }
}

__global__ __launch_bounds__(256) void k_proj(
    const float* __restrict__ s, const float* __restrict__ quat, const float* __restrict__ trans,
    const float* __restrict__ Wqs, const float* __restrict__ Wks, const float* __restrict__ Wvs,
    const float* __restrict__ Wqv, const float* __restrict__ Wkv, const float* __restrict__ Wvv,
    unsigned* __restrict__ qs, unsigned* __restrict__ ks, float* __restrict__ vs,
    unsigned* __restrict__ qv, unsigned* __restrict__ kv, float* __restrict__ vv, int n)
{
  __shared__ float stT[64][40];    // transposed s tile (k-major), 16B-aligned cols
  __shared__ float pt[BN][97];     // point staging (x:0..31, y:32..63, z:64..95)
  const int tid = threadIdx.x;
  const int node0 = blockIdx.x * BN;

  #pragma unroll
  for (int r = 0; r < 2; ++r){
    const int idx = tid + r*256;          // float4 index
    const int nd = idx >> 4, c4 = idx & 15;
    const int g = node0 + nd;
    float4 v = make_float4(0.f,0.f,0.f,0.f);
    if (g < n) v = *(const float4*)(s + (size_t)g*64 + c4*4);
    stT[c4*4+0][nd]=v.x; stT[c4*4+1][nd]=v.y; stT[c4*4+2][nd]=v.z; stT[c4*4+3][nd]=v.w;
  }
  __syncthreads();

  const int cg = tid & 63, sl = tid >> 6;
  const int cgp = tid & 31, slp = tid >> 5;
  float acc[8][4];

  pass256(Wqs, stT, cg, sl, acc);
  #pragma unroll
  for (int i=0;i<8;i++){
    const int g = node0 + sl*8 + i;
    if (g < n){
      uint2 u; u.x = pack2(acc[i][0],acc[i][1]); u.y = pack2(acc[i][2],acc[i][3]);
      *(uint2*)(qs + (size_t)g*128 + cg*2) = u;
    }
  }
  pass256(Wks, stT, cg, sl, acc);
  #pragma unroll
  for (int i=0;i<8;i++){
    const int g = node0 + sl*8 + i;
    if (g < n){
      uint2 u; u.x = pack2(acc[i][0],acc[i][1]); u.y = pack2(acc[i][2],acc[i][3]);
      *(uint2*)(ks + (size_t)g*128 + cg*2) = u;
    }
  }
  pass256(Wvs, stT, cg, sl, acc);
  #pragma unroll
  for (int i=0;i<8;i++){
    const int g = node0 + sl*8 + i;
    if (g < n){
      float4 f; f.x=acc[i][0]; f.y=acc[i][1]; f.z=acc[i][2]; f.w=acc[i][3];
      *(float4*)(vs + (size_t)g*256 + cg*4) = f;
    }
  }

  float pac[4][4];

  // q_v: rotate + translate -> bf16
  pass96(Wqv, stT, cgp, slp, pac);
  __syncthreads();
  if (cgp < 24){
    #pragma unroll
    for (int i=0;i<4;i++){
      #pragma unroll
      for (int c=0;c<4;c++) pt[slp*4+i][cgp*4+c] = pac[i][c];
    }
  }
  __syncthreads();
  #pragma unroll
  for (int r = 0; r < 2; ++r){
    const int t2 = tid + r*256;
    const int nd = t2 >> 4, pp = t2 & 15;
    const int g = node0 + nd;
    if (g < n){
      const float4 q4 = *(const float4*)(quat + (size_t)g*4);
      const float tx = trans[(size_t)g*3], ty = trans[(size_t)g*3+1], tz = trans[(size_t)g*3+2];
      float x0,y0,z0,x1,y1,z1;
      quat_rot(q4.x,q4.y,q4.z,q4.w, pt[nd][2*pp],   pt[nd][32+2*pp],   pt[nd][64+2*pp],   x0,y0,z0);
      quat_rot(q4.x,q4.y,q4.z,q4.w, pt[nd][2*pp+1], pt[nd][32+2*pp+1], pt[nd][64+2*pp+1], x1,y1,z1);
      x0+=tx; y0+=ty; z0+=tz; x1+=tx; y1+=ty; z1+=tz;
      unsigned* d = qv + (size_t)g*48 + pp*3;
      d[0] = pack2(x0,y0); d[1] = pack2(z0,x1); d[2] = pack2(y1,z1);
    }
  }

  // k_v: rotate + translate -> bf16
  pass96(Wkv, stT, cgp, slp, pac);
  __syncthreads();
  if (cgp < 24){
    #pragma unroll
    for (int i=0;i<4;i++){
      #pragma unroll
      for (int c=0;c<4;c++) pt[slp*4+i][cgp*4+c] = pac[i][c];
    }
  }
  __syncthreads();
  #pragma unroll
  for (int r = 0; r < 2; ++r){
    const int t2 = tid + r*256;
    const int nd = t2 >> 4, pp = t2 & 15;
    const int g = node0 + nd;
    if (g < n){
      const float4 q4 = *(const float4*)(quat + (size_t)g*4);
      const float tx = trans[(size_t)g*3], ty = trans[(size_t)g*3+1], tz = trans[(size_t)g*3+2];
      float x0,y0,z0,x1,y1,z1;
      quat_rot(q4.x,q4.y,q4.z,q4.w, pt[nd][2*pp],   pt[nd][32+2*pp],   pt[nd][64+2*pp],   x0,y0,z0);
      quat_rot(q4.x,q4.y,q4.z,q4.w, pt[nd][2*pp+1], pt[nd][32+2*pp+1], pt[nd][64+2*pp+1], x1,y1,z1);
      x0+=tx; y0+=ty; z0+=tz; x1+=tx; y1+=ty; z1+=tz;
      unsigned* d = kv + (size_t)g*48 + pp*3;
      d[0] = pack2(x0,y0); d[1] = pack2(z0,x1); d[2] = pack2(y1,z1);
    }
  }

  // v_v: raw (pre-rotation) points == out_vec; f32 PLANE layout
  pass96(Wvv, stT, cgp, slp, pac);
  __syncthreads();
  if (cgp < 24){
    #pragma unroll
    for (int i=0;i<4;i++){
      #pragma unroll
      for (int c=0;c<4;c++) pt[slp*4+i][cgp*4+c] = pac[i][c];
    }
  }
  __syncthreads();
  #pragma unroll
  for (int r = 0; r < 12; ++r){
    const int idx = tid + r*256;
    const int nd = idx / 96, col = idx - nd*96;
    const int g = node0 + nd;
    if (g < n) vv[(size_t)g*96 + col] = pt[nd][col];
  }
}

// ---------------- z projection + CSR fill (k_zf) ---------------------------
// Block = 256 threads = 256 original-order edges.  Single-buffered LDS z tile
// (16.5 KB) -> high occupancy.  Record per edge at CSR pos (16 uints):
//   [0:4)  logits/bias f32 x4
//   [4:12) pz bf16 x16
//   [12]   i   [13] j   [14:16) pad

__global__ __launch_bounds__(256) void k_zf(
    const int* __restrict__ ei, const unsigned* __restrict__ rank,
    const unsigned* __restrict__ roff, const float* __restrict__ z,
    const float* __restrict__ Wb,  const float* __restrict__ bb,
    const float* __restrict__ Wdz, const float* __restrict__ bdz,
    unsigned* __restrict__ rec, int ne)
{
  __shared__ float zT[16][258];   // one 16-k chunk, transposed, padded
  const int tid = threadIdx.x;
  const int E0  = blockIdx.x * 256;
  const int e   = E0 + tid;
  const bool full = (E0 + 256 <= ne);

  int i = 0, j = 0; unsigned pos = 0;
  if (e < ne){
    i = ei[e]; j = ei[ne + e];
    pos = roff[i] + rank[e];
  }

  float b4[4] = {0.f,0.f,0.f,0.f};
  float pacc[16];
  #pragma unroll
  for (int c=0;c<16;c++) pacc[c]=0.f;

  if (full){
    #pragma unroll
    for (int c = 0; c < 4; ++c){
      if (c) __syncthreads();
      #pragma unroll
      for (int q = 0; q < 4; ++q){
        const int idx = tid + q*256;           // 0..1023
        const int row = idx >> 2, f4 = idx & 3;
        const float4 v = *(const float4*)(z + (size_t)(E0+row)*64 + c*16 + f4*4);
        zT[f4*4+0][row]=v.x; zT[f4*4+1][row]=v.y;
        zT[f4*4+2][row]=v.z; zT[f4*4+3][row]=v.w;
      }
      __syncthreads();
      const int kb = c*16;
      #pragma unroll
      for (int kk = 0; kk < 16; ++kk){
        const float zk = zT[kk][tid];
        const int k = kb + kk;
        const float4 wb = *(const float4*)(Wb + k*4);
        b4[0]+=zk*wb.x; b4[1]+=zk*wb.y; b4[2]+=zk*wb.z; b4[3]+=zk*wb.w;
        const float* wd = Wdz + k*16;
        const float4 w0=*(const float4*)(wd),   w1=*(const float4*)(wd+4),
                     w2=*(const float4*)(wd+8), w3=*(const float4*)(wd+12);
        pacc[ 0]+=zk*w0.x; pacc[ 1]+=zk*w0.y; pacc[ 2]+=zk*w0.z; pacc[ 3]+=zk*w0.w;
        pacc[ 4]+=zk*w1.x; pacc[ 5]+=zk*w1.y; pacc[ 6]+=zk*w1.z; pacc[ 7]+=zk*w1.w;
        pacc[ 8]+=zk*w2.x; pacc[ 9]+=zk*w2.y; pacc[10]+=zk*w2.z; pacc[11]+=zk*w2.w;
        pacc[12]+=zk*w3.x; pacc[13]+=zk*w3.y; pacc[14]+=zk*w3.z; pacc[15]+=zk*w3.w;
      }
    }
  } else if (e < ne){
    const float* zr = z + (size_t)e*64;
    for (int k4 = 0; k4 < 16; ++k4){
      const float4 zv = *(const float4*)(zr + 4*k4);
      #pragma unroll
      for (int kk = 0; kk < 4; ++kk){
        const int k = 4*k4 + kk;
        const float zk = (kk==0)?zv.x:((kk==1)?zv.y:((kk==2)?zv.z:zv.w));
        const float4 wb = *(const float4*)(Wb + k*4);
        b4[0]+=zk*wb.x; b4[1]+=zk*wb.y; b4[2]+=zk*wb.z; b4[3]+=zk*wb.w;
        const float* wd = Wdz + k*16;
        const float4 w0=*(const float4*)(wd),   w1=*(const float4*)(wd+4),
                     w2=*(const float4*)(wd+8), w3=*(const float4*)(wd+12);
        pacc[ 0]+=zk*w0.x; pacc[ 1]+=zk*w0.y; pacc[ 2]+=zk*w0.z; pacc[ 3]+=zk*w0.w;
        pacc[ 4]+=zk*w1.x; pacc[ 5]+=zk*w1.y; pacc[ 6]+=zk*w1.z; pacc[ 7]+=zk*w1.w;
        pacc[ 8]+=zk*w2.x; pacc[ 9]+=zk*w2.y; pacc[10]+=zk*w2.z; pacc[11]+=zk*w2.w;
        pacc[12]+=zk*w3.x; pacc[13]+=zk*w3.y; pacc[14]+=zk*w3.z; pacc[15]+=zk*w3.w;
      }
    }
  }

  if (e < ne){
    #pragma unroll
    for (int c=0;c<16;c++) pacc[c] += bdz[c];
    uint4 u0, u1;
    u0.x=pack2(pacc[0],pacc[1]);   u0.y=pack2(pacc[2],pacc[3]);
    u0.z=pack2(pacc[4],pacc[5]);   u0.w=pack2(pacc[6],pacc[7]);
    u1.x=pack2(pacc[8],pacc[9]);   u1.y=pack2(pacc[10],pacc[11]);
    u1.z=pack2(pacc[12],pacc[13]); u1.w=pack2(pacc[14],pacc[15]);
    float4 bo;
    bo.x = C_SQRT13*(b4[0] + bb[0]);
    bo.y = C_SQRT13*(b4[1] + bb[1]);
    bo.z = C_SQRT13*(b4[2] + bb[2]);
    bo.w = C_SQRT13*(b4[3] + bb[3]);
    uint4* d = (uint4*)rec + (size_t)pos*4;
    d[0] = *(uint4*)&bo;
    d[1] = u0;
    d[2] = u1;
    d[3] = make_uint4((unsigned)i, (unsigned)j, 0u, 0u);
  }
}

// ------------------------------- edge kernel -------------------------------
// CSR order: consecutive edges share i -> ks[i]/qv[i] L1-resident.  4-lane-
// per-edge split: group g = lane>>2 handles edge el = sb*16+g of its wave,
// lane c = lane&3 reads 16-B slices (4 lanes cover a 64-B line).

__global__ __launch_bounds__(256) void k_edge(
    const float* __restrict__ hwts,
    const unsigned* __restrict__ qs, const unsigned* __restrict__ ks,
    const unsigned* __restrict__ qv, const unsigned* __restrict__ kv,
    unsigned* __restrict__ rec, int ne)
{
  const int tid = threadIdx.x;
  const int P0  = blockIdx.x * 256;
  const int p   = P0 + tid;
  const bool full = (P0 + 256 <= ne);

  // folded softplus head weights (include C_VEC)
  const float hw0 = C_VEC * log1pf(__expf(hwts[0]));
  const float hw1 = C_VEC * log1pf(__expf(hwts[1]));
  const float hw2 = C_VEC * log1pf(__expf(hwts[2]));
  const float hw3 = C_VEC * log1pf(__expf(hwts[3]));

  int i = 0, j = 0;
  float4 bias = make_float4(0.f,0.f,0.f,0.f);
  if (p < ne){
    bias = *(const float4*)((const float*)rec + (size_t)p*16);
    const uint2 ij = *(const uint2*)(rec + (size_t)p*16 + 12);
    i = (int)ij.x; j = (int)ij.y;
  }

  if (full){
    const int l = tid & 63;
    const int c = l & 3, g = l >> 2;
    #pragma unroll
    for (int sb = 0; sb < 4; ++sb){
      const int el = sb*16 + g;
      const int ie = __shfl(i, el, 64);
      const int je = __shfl(j, el, 64);

      // scalar dot (heads from k-slice index, compile-time per it)
      const uint4* kr = (const uint4*)ks + (size_t)ie*32;
      const uint4* qr = (const uint4*)qs + (size_t)je*32;
      float s0=0.f, s1=0.f, s2=0.f, s3=0.f;
      #pragma unroll
      for (int it = 0; it < 8; ++it){
        const uint4 a = kr[it*4 + c];
        const uint4 b = qr[it*4 + c];
        float d;
        d  = bflo(a.x)*bflo(b.x) + bfhi(a.x)*bfhi(b.x);
        d += bflo(a.y)*bflo(b.y) + bfhi(a.y)*bfhi(b.y);
        d += bflo(a.z)*bflo(b.z) + bfhi(a.z)*bfhi(b.z);
        d += bflo(a.w)*bflo(b.w) + bfhi(a.w)*bfhi(b.w);
        if      (it < 2) s0 += d;
        else if (it < 4) s1 += d;
        else if (it < 6) s2 += d;
        else             s3 += d;
      }

      // vector attention (head = uint4-idx/3; uint4-idx = chunk*4+c)
      const uint4* qvr = (const uint4*)qv + (size_t)ie*12;
      const uint4* kvr = (const uint4*)kv + (size_t)je*12;
      float v0=0.f, v1=0.f, v2=0.f, v3=0.f;
      {
        const uint4 a = qvr[c], b = kvr[c];
        float d, t;
        t = bflo(a.x)-bflo(b.x); d  = t*t;  t = bfhi(a.x)-bfhi(b.x); d += t*t;
        t = bflo(a.y)-bflo(b.y); d += t*t;  t = bfhi(a.y)-bfhi(b.y); d += t*t;
        t = bflo(a.z)-bflo(b.z); d += t*t;  t = bfhi(a.z)-bfhi(b.z); d += t*t;
        t = bflo(a.w)-bflo(b.w); d += t*t;  t = bfhi(a.w)-bfhi(b.w); d += t*t;
        if (c < 3) v0 += d; else v1 += d;
      }
      {
        const uint4 a = qvr[4+c], b = kvr[4+c];
        float d, t;
        t = bflo(a.x)-bflo(b.x); d  = t*t;  t = bfhi(a.x)-bfhi(b.x); d += t*t;
        t = bflo(a.y)-bflo(b.y); d += t*t;  t = bfhi(a.y)-bfhi(b.y); d += t*t;
        t = bflo(a.z)-bflo(b.z); d += t*t;  t = bfhi(a.z)-bfhi(b.z); d += t*t;
        t = bflo(a.w)-bflo(b.w); d += t*t;  t = bfhi(a.w)-bfhi(b.w); d += t*t;
        if (c < 2) v1 += d; else v2 += d;
      }
      {
        const uint4 a = qvr[8+c], b = kvr[8+c];
        float d, t;
        t = bflo(a.x)-bflo(b.x); d  = t*t;  t = bfhi(a.x)-bfhi(b.x); d += t*t;
        t = bflo(a.y)-bflo(b.y); d += t*t;  t = bfhi(a.y)-bfhi(b.y); d += t*t;
        t = bflo(a.z)-bflo(b.z); d += t*t;  t = bfhi(a.z)-bfhi(b.z); d += t*t;
        t = bflo(a.w)-bflo(b.w); d += t*t;  t = bfhi(a.w)-bfhi(b.w); d += t*t;
        if (c < 1) v2 += d; else v3 += d;
      }

      // fold per-head partial logit, reduce across the 4 lanes of the group
      float p0 = C_SQRT83*s0 + hw0*v0;
      float p1 = C_SQRT83*s1 + hw1*v1;
      float p2 = C_SQRT83*s2 + hw2*v2;
      float p3 = C_SQRT83*s3 + hw3*v3;
      #pragma unroll
      for (int msk = 1; msk < 4; msk <<= 1){
        p0 += __shfl_xor(p0, msk, 64);
        p1 += __shfl_xor(p1, msk, 64);
        p2 += __shfl_xor(p2, msk, 64);
        p3 += __shfl_xor(p3, msk, 64);
      }
      const float pc = (c==0)?p0:((c==1)?p1:((c==2)?p2:p3));

      // route the 4 head-logits back to the owning lane (owners: l>>4 == sb)
      const int srcbase = (l & 15) << 2;
      const float q0 = __shfl(pc, srcbase+0, 64);
      const float q1 = __shfl(pc, srcbase+1, 64);
      const float q2 = __shfl(pc, srcbase+2, 64);
      const float q3 = __shfl(pc, srcbase+3, 64);
      if ((l >> 4) == sb){
        float4 lg; lg.x = q0 + bias.x; lg.y = q1 + bias.y;
        lg.z = q2 + bias.z; lg.w = q3 + bias.w;
        *((uint4*)rec + (size_t)p*4) = *(uint4*)&lg;
      }
    }
  } else if (p < ne){
    // tail block: per-thread gather (never hit when ne % 256 == 0)
    const uint4* kr = (const uint4*)ks + (size_t)i*32;
    const uint4* qr = (const uint4*)qs + (size_t)j*32;
    float sdot[4];
    #pragma unroll
    for (int h = 0; h < 4; ++h){
      float acc = 0.f;
      #pragma unroll
      for (int cc = 0; cc < 8; ++cc){
        const uint4 a = kr[h*8+cc];
        const uint4 b = qr[h*8+cc];
        acc += bflo(a.x)*bflo(b.x) + bfhi(a.x)*bfhi(b.x);
        acc += bflo(a.y)*bflo(b.y) + bfhi(a.y)*bfhi(b.y);
        acc += bflo(a.z)*bflo(b.z) + bfhi(a.z)*bfhi(b.z);
        acc += bflo(a.w)*bflo(b.w) + bfhi(a.w)*bfhi(b.w);
      }
      sdot[h] = acc;
    }
    const uint4* qvr = (const uint4*)qv + (size_t)i*12;
    const uint4* kvr = (const uint4*)kv + (size_t)j*12;
    float vsum[4];
    #pragma unroll
    for (int h = 0; h < 4; ++h){
      float acc = 0.f;
      #pragma unroll
      for (int cc = 0; cc < 3; ++cc){
        const uint4 a = qvr[h*3+cc];
        const uint4 b = kvr[h*3+cc];
        float d;
        d = bflo(a.x)-bflo(b.x); acc += d*d;  d = bfhi(a.x)-bfhi(b.x); acc += d*d;
        d = bflo(a.y)-bflo(b.y); acc += d*d;  d = bfhi(a.y)-bfhi(b.y); acc += d*d;
        d = bflo(a.z)-bflo(b.z); acc += d*d;  d = bfhi(a.z)-bfhi(b.z); acc += d*d;
        d = bflo(a.w)-bflo(b.w); acc += d*d;  d = bfhi(a.w)-bfhi(b.w); acc += d*d;
      }
      vsum[h] = acc;
    }
    float4 lg;
    lg.x = C_SQRT83*sdot[0] + bias.x + hw0*vsum[0];
    lg.y = C_SQRT83*sdot[1] + bias.y + hw1*vsum[1];
    lg.z = C_SQRT83*sdot[2] + bias.z + hw2*vsum[2];
    lg.w = C_SQRT83*sdot[3] + bias.w + hw3*vsum[3];
    *((uint4*)rec + (size_t)p*4) = *(uint4*)&lg;
  }
}

// ----------------------- wave-per-node softmax + pair -----------------------
// rec layout per edge: uint[16] = {logits f32 x4, pz bf16 x16 (8 uints), i, j, pad}

__global__ __launch_bounds__(256) void k_soft(
    const unsigned* __restrict__ rec,
    const unsigned* __restrict__ row_off, float* __restrict__ out_pair, int n)
{
  const int node = blockIdx.x*4 + (threadIdx.x >> 6);
  if (node >= n) return;
  const int lane = threadIdx.x & 63;
  const int beg = (int)row_off[node], end = (int)row_off[node+1];
  const float* recf = (const float*)rec;

  // ---- phase 1: per-head max and sum (lane-parallel over edges) ----
  float m[4] = {-3.0e38f,-3.0e38f,-3.0e38f,-3.0e38f};
  for (int p = beg + lane; p < end; p += 64){
    const float4 l = *(const float4*)(recf + (size_t)p*16);
    m[0]=fmaxf(m[0],l.x); m[1]=fmaxf(m[1],l.y); m[2]=fmaxf(m[2],l.z); m[3]=fmaxf(m[3],l.w);
  }
  #pragma unroll
  for (int msk = 1; msk < 64; msk <<= 1){
    #pragma unroll
    for (int h=0;h<4;h++) m[h] = fmaxf(m[h], __shfl_xor(m[h], msk));
  }
  float S[4] = {0.f,0.f,0.f,0.f};
  for (int p = beg + lane; p < end; p += 64){
    const float4 l = *(const float4*)(recf + (size_t)p*16);
    S[0]+=__expf(l.x-m[0]); S[1]+=__expf(l.y-m[1]);
    S[2]+=__expf(l.z-m[2]); S[3]+=__expf(l.w-m[3]);
  }
  #pragma unroll
  for (int msk = 1; msk < 64; msk <<= 1){
    #pragma unroll
    for (int h=0;h<4;h++) S[h] += __shfl_xor(S[h], msk);
  }
  float inv[4];
  #pragma unroll
  for (int h=0;h<4;h++) inv[h] = (S[h] > 0.f) ? (1.f/S[h]) : 0.f;

  // ---- phase 2: weighted pair aggregation ----
  const int e4 = lane >> 4, c = lane & 15;
  float acc[4] = {0.f,0.f,0.f,0.f};
  for (int base = beg; base < end; base += 4){
    const int p = base + e4;
    if (p < end){
      const float4 l = *(const float4*)(recf + (size_t)p*16);
      const unsigned u = rec[(size_t)p*16 + 4 + (c>>1)];
      const float pzv = (c & 1) ? bfhi(u) : bflo(u);
      acc[0] += __expf(l.x-m[0]) * pzv;
      acc[1] += __expf(l.y-m[1]) * pzv;
      acc[2] += __expf(l.z-m[2]) * pzv;
      acc[3] += __expf(l.w-m[3]) * pzv;
    }
  }
  #pragma unroll
  for (int msk = 16; msk < 64; msk <<= 1){
    #pragma unroll
    for (int h=0;h<4;h++) acc[h] += __shfl_xor(acc[h], msk);
  }
  const int hOut = lane >> 4;          // output layout: [h*16 + c]
  out_pair[(size_t)node*64 + lane] = acc[hOut] * inv[hOut];
}

// --------------------- feats assembly + output GEMM ------------------------

__global__ __launch_bounds__(256) void k_out(
    const float* __restrict__ vs, const float* __restrict__ vv,
    const float* __restrict__ out_pair, const unsigned* __restrict__ row_off,
    const float* __restrict__ quat, const float* __restrict__ trans,
    const float* __restrict__ Wout, const float* __restrict__ bout,
    float* __restrict__ out, int n)
{
  __shared__ float feats[32][448];
  __shared__ int degs[32];
  const int tid = threadIdx.x;
  const int node0 = blockIdx.x*32;

  if (tid < 32){
    const int g = node0 + tid;
    degs[tid] = (g < n) ? (int)(row_off[g+1] - row_off[g]) : 1;
  }
  __syncthreads();

  for (int x = tid; x < 32*256; x += 256){
    const int nd = x >> 8, c = x & 255;
    const int g = node0 + nd;
    feats[nd][c] = (g < n && degs[nd] > 0) ? vs[(size_t)g*256 + c] : 0.f;
  }
  for (int x = tid; x < 32*64; x += 256){
    const int nd = x >> 6, c = x & 63;
    const int g = node0 + nd;
    feats[nd][384 + c] = (g < n) ? out_pair[(size_t)g*64 + c] : 0.f;
  }
  for (int x = tid; x < 32*32; x += 256){
    const int nd = x >> 5, pt = x & 31;
    const int g = node0 + nd;
    float X=0.f, Y=0.f, Z=0.f;
    if (g < n){
      if (degs[nd] > 0){
        X = vv[(size_t)g*96 + pt];
        Y = vv[(size_t)g*96 + 32 + pt];
        Z = vv[(size_t)g*96 + 64 + pt];
      } else {
        const float4 q4 = *(const float4*)(quat + (size_t)g*4);
        const float tx = trans[(size_t)g*3], ty = trans[(size_t)g*3+1], tz = trans[(size_t)g*3+2];
        quat_rot(q4.x, -q4.y, -q4.z, -q4.w, -tx, -ty, -tz, X, Y, Z);
      }
    }
    feats[nd][256 + pt] = X;
    feats[nd][288 + pt] = Y;
    feats[nd][320 + pt] = Z;
    feats[nd][352 + pt] = sqrtf(X*X + Y*Y + Z*Z + 1e-8f);
  }
  __syncthreads();

  const int lane = tid & 63;
  const int wave = tid >> 6;
  float acc[8];
  #pragma unroll
  for (int q8=0;q8<8;q8++) acc[q8]=0.f;

  for (int k0 = 0; k0 < 448; k0 += 4){
    const float w0 = Wout[(size_t)(k0+0)*64 + lane];
    const float w1 = Wout[(size_t)(k0+1)*64 + lane];
    const float w2 = Wout[(size_t)(k0+2)*64 + lane];
    const float w3 = Wout[(size_t)(k0+3)*64 + lane];
    #pragma unroll
    for (int q8 = 0; q8 < 8; ++q8){
      const float4 f = *(const float4*)&feats[wave*8 + q8][k0];
      acc[q8] += f.x*w0 + f.y*w1 + f.z*w2 + f.w*w3;
    }
  }
  const float bo = bout[lane];
  #pragma unroll
  for (int q8 = 0; q8 < 8; ++q8){
    const int g = node0 + wave*8 + q8;
    if (g < n) out[(size_t)g*64 + lane] = acc[q8] + bo;
  }
}

// --------------------------------- launch ----------------------------------

extern "C" void kernel_launch(void* const* d_in, const int* in_sizes, int n_in,
                              void* d_out, int out_size, void* d_ws, size_t ws_size,
                              hipStream_t stream) {
  const float* s     = (const float*)d_in[0];
  const float* z     = (const float*)d_in[1];
  const int*   ei    = (const int*)  d_in[2];
  const float* quat  = (const float*)d_in[3];
  const float* trans = (const float*)d_in[4];
  const float* Wqs   = (const float*)d_in[5];
  const float* Wks   = (const float*)d_in[6];
  const float* Wvs   = (const float*)d_in[7];
  const float* Wqv   = (const float*)d_in[8];
  const float* Wkv   = (const float*)d_in[9];
  const float* Wvv   = (const float*)d_in[10];
  const float* Wb    = (const float*)d_in[11];
  const float* bb    = (const float*)d_in[12];
  const float* Wdz   = (const float*)d_in[13];
  const float* bdz   = (const float*)d_in[14];
  const float* hwts  = (const float*)d_in[15];
  const float* Wout  = (const float*)d_in[16];
  const float* bout  = (const float*)d_in[17];
  float* out = (float*)d_out;

  const int n  = in_sizes[0] / 64;   // 20000
  const int ne = in_sizes[1] / 64;   // 640000

  size_t off = 0;
  char* base = (char*)d_ws;
  auto take = [&](size_t bytes)->char* {
    char* p = base + off;
    off += (bytes + 255) & ~(size_t)255;
    return p;
  };
  unsigned* qs     = (unsigned*)take((size_t)n*512);    // bf16 N x 256
  unsigned* ks     = (unsigned*)take((size_t)n*512);    // bf16 N x 256
  unsigned* qvt    = (unsigned*)take((size_t)n*192);    // bf16 N x 96 (rot + t)
  unsigned* kvt    = (unsigned*)take((size_t)n*192);    // bf16 N x 96 (rot + t)
  float*    vs     = (float*)   take((size_t)n*1024);   // f32  N x 256
  float*    vv     = (float*)   take((size_t)n*384);    // f32  N x 96 (raw, planes)
  unsigned* rec    = (unsigned*)take((size_t)ne*64);    // 64-B record per edge
  unsigned* counts = (unsigned*)take((size_t)n*4);
  unsigned* roff   = (unsigned*)take((size_t)(n+1)*4);
  unsigned* rank   = (unsigned*)take((size_t)ne*4);
  float*    opair  = (float*)   take((size_t)n*256);    // f32  N x 64
  (void)ws_size; (void)n_in; (void)out_size;

  const int gbE = (ne + 255) / 256;

  hipMemsetAsync(counts, 0, (size_t)n*4, stream);
  k_count<<<gbE, 256, 0, stream>>>(ei, counts, rank, ne);
  k_scan <<<1,   256, 0, stream>>>(counts, roff, n);
  k_proj <<<(n + BN - 1)/BN, 256, 0, stream>>>(s, quat, trans, Wqs, Wks, Wvs, Wqv, Wkv, Wvv,
                                               qs, ks, vs, qvt, kvt, vv, n);
  k_zf   <<<gbE, 256, 0, stream>>>(ei, rank, roff, z, Wb, bb, Wdz, bdz, rec, ne);
  k_edge <<<gbE, 256, 0, stream>>>(hwts, qs, ks, qvt, kvt, rec, ne);
  k_soft <<<(n + 3)/4, 256, 0, stream>>>(rec, roff, opair, n);
  k_out  <<<(n + 31)/32, 256, 0, stream>>>(vs, vv, opair, roff, quat, trans,
                                           Wout, bout, out, n);
}

// Round 5
// 590.993 us; speedup vs baseline: 1.1880x; 1.0124x over previous
//
#include <hip/hip_runtime.h>
#include <stdint.h>

// ---------------------------------------------------------------------------
// InvariantPointAttention, N=20000 nodes, E=640000 edges, H=4, S=64, QK=VD=8
//
// Pipeline (all on `stream`):
//   memset(counts) / k_count / k_scan : CSR build.  k_count stores rank[e]
//       (atomic return).
//   k_proj   : tiled per-node projections (32 nodes/block, transposed LDS
//              s-tile): q_s,k_s (bf16 Nx256), q_v,k_v (rot+trans bf16 Nx96),
//              v_s (f32 Nx256), v_loc (raw points f32 Nx96, PLANE layout).
//   k_zf     : per ORIGINAL edge e (coalesced z stream via single-buffered
//              16.5 KB LDS transpose tile + register prefetch of the next
//              chunk: HBM latency hides under the 320-FMA compute phase):
//              z@Wb -> bias -> lg[pos] (dense logits array, scattered 16B);
//              z@Wdz -> pz -> rec{pz bf16x16, i, j} (48B burst, 1 line).
//   k_edge   : per CSR edge.  bias read from lg[p] (coalesced!), i,j from rec;
//              4-lane-per-edge split gathers (16 lines/instr); final logits
//              written back to lg[p] (coalesced).  No LDS -> high occupancy.
//   k_soft   : wave-per-node, register/shuffle only softmax + pair
//              aggregation; phase 1 streams DENSE lg (fully coalesced).
//   k_out    : 16 nodes/block (28.7 KB LDS -> 5 blocks/CU, fixes the 13%
//              occupancy latency wall): feats[448] + feats @ Wout + bout.
// ---------------------------------------------------------------------------

#define C_SQRT83  1.6329931618554518f   // sqrt(8/3)
#define C_SQRT13  0.5773502691896258f   // sqrt(1/3)
#define C_VEC    -0.04811252243246881f  // -0.5*sqrt(1/108)

__device__ __forceinline__ unsigned short f2bf(float f){
  unsigned u = __float_as_uint(f);
  u += 0x7fffu + ((u >> 16) & 1u);          // round-to-nearest-even
  return (unsigned short)(u >> 16);
}
__device__ __forceinline__ unsigned pack2(float a, float b){
  return (unsigned)f2bf(a) | ((unsigned)f2bf(b) << 16);
}
__device__ __forceinline__ float bflo(unsigned u){ return __uint_as_float(u << 16); }
__device__ __forceinline__ float bfhi(unsigned u){ return __uint_as_float(u & 0xffff0000u); }

__device__ __forceinline__ void quat_rot(float w, float ux, float uy, float uz,
                                         float vx, float vy, float vz,
                                         float& ox, float& oy, float& oz){
  float cx = uy*vz - uz*vy;
  float cy = uz*vx - ux*vz;
  float cz = ux*vy - uy*vx;
  float dx = uy*cz - uz*cy;
  float dy = uz*cx - ux*cz;
  float dz = ux*cy - uy*cx;
  ox = vx + 2.f*(w*cx + dx);
  oy = vy + 2.f*(w*cy + dy);
  oz = vz + 2.f*(w*cz + dz);
}

// -------------------------------- CSR build --------------------------------

__global__ __launch_bounds__(256) void k_count(const int* __restrict__ ei,
                                               unsigned* __restrict__ counts,
                                               unsigned* __restrict__ rank, int ne){
  int e = blockIdx.x*256 + threadIdx.x;
  if (e >= ne) return;
  rank[e] = atomicAdd(&counts[ei[e]], 1u);
}

__global__ __launch_bounds__(256) void k_scan(const unsigned* __restrict__ counts,
                                              unsigned* __restrict__ row_off, int n){
  __shared__ unsigned part[256];
  int t = threadIdx.x;
  int chunk = (n + 255) >> 8;
  int s0 = t*chunk, s1 = min(s0 + chunk, n);
  unsigned sum = 0;
  for (int k = s0; k < s1; ++k) sum += counts[k];
  part[t] = sum; __syncthreads();
  for (int off = 1; off < 256; off <<= 1){
    unsigned v = (t >= off) ? part[t-off] : 0u;
    __syncthreads();
    part[t] += v;
    __syncthreads();
  }
  unsigned run = (t == 0) ? 0u : part[t-1];
  for (int k = s0; k < s1; ++k){
    row_off[k] = run; run += counts[k];
  }
  if (t == 255) row_off[n] = part[255];
}

// ------------------------------ node projections ----------------------------
// Block = 32 nodes, 256 threads.  s tile TRANSPOSED in LDS: stT[k][node].

#define BN 32

__device__ __forceinline__ void pass256(const float* __restrict__ W,
                                        const float stT[64][40], int cg, int sl,
                                        float acc[8][4]){
  #pragma unroll
  for (int i=0;i<8;i++){ acc[i][0]=0.f; acc[i][1]=0.f; acc[i][2]=0.f; acc[i][3]=0.f; }
  #pragma unroll 4
  for (int k = 0; k < 64; ++k){
    const float4 w  = *(const float4*)(W + (size_t)k*256 + cg*4);
    const float4 n0 = *(const float4*)&stT[k][sl*8];
    const float4 n1 = *(const float4*)&stT[k][sl*8+4];
    acc[0][0]+=n0.x*w.x; acc[0][1]+=n0.x*w.y; acc[0][2]+=n0.x*w.z; acc[0][3]+=n0.x*w.w;
    acc[1][0]+=n0.y*w.x; acc[1][1]+=n0.y*w.y; acc[1][2]+=n0.y*w.z; acc[1][3]+=n0.y*w.w;
    acc[2][0]+=n0.z*w.x; acc[2][1]+=n0.z*w.y; acc[2][2]+=n0.z*w.z; acc[2][3]+=n0.z*w.w;
    acc[3][0]+=n0.w*w.x; acc[3][1]+=n0.w*w.y; acc[3][2]+=n0.w*w.z; acc[3][3]+=n0.w*w.w;
    acc[4][0]+=n1.x*w.x; acc[4][1]+=n1.x*w.y; acc[4][2]+=n1.x*w.z; acc[4][3]+=n1.x*w.w;
    acc[5][0]+=n1.y*w.x; acc[5][1]+=n1.y*w.y; acc[5][2]+=n1.y*w.z; acc[5][3]+=n1.y*w.w;
    acc[6][0]+=n1.z*w.x; acc[6][1]+=n1.z*w.y; acc[6][2]+=n1.z*w.z; acc[6][3]+=n1.z*w.w;
    acc[7][0]+=n1.w*w.x; acc[7][1]+=n1.w*w.y; acc[7][2]+=n1.w*w.z; acc[7][3]+=n1.w*w.w;
  }
}

__device__ __forceinline__ void pass96(const float* __restrict__ W,
                                       const float stT[64][40], int cgp, int slp,
                                       float acc[4][4]){
  #pragma unroll
  for (int i=0;i<4;i++){ acc[i][0]=0.f; acc[i][1]=0.f; acc[i][2]=0.f; acc[i][3]=0.f; }
  if (cgp >= 24) return;
  #pragma unroll 4
  for (int k = 0; k < 64; ++k){
    const float4 w = *(const float4*)(W + (size_t)k*96 + cgp*4);
    const float4 nv = *(const float4*)&stT[k][slp*4];
    acc[0][0]+=nv.x*w.x; acc[0][1]+=nv.x*w.y; acc[0][2]+=nv.x*w.z; acc[0][3]+=nv.x*w.w;
    acc[1][0]+=nv.y*w.x; acc[1][1]+=nv.y*w.y; acc[1][2]+=nv.y*w.z; acc[1][3]+=nv.y*w.w;
    acc[2][0]+=nv.z*w.x; acc[2][1]+=nv.z*w.y; acc[2][2]+=nv.z*w.z; acc[2][3]+=nv.z*w.w;
    acc[3][0]+=nv.w*w.x; acc[3][1]+=nv.w*w.y; acc[3][2]+=nv.w*w.z; acc[3][3]+=nv.w*w.w;
  }
}

__global__ __launch_bounds__(256) void k_proj(
    const float* __restrict__ s, const float* __restrict__ quat, const float* __restrict__ trans,
    const float* __restrict__ Wqs, const float* __restrict__ Wks, const float* __restrict__ Wvs,
    const float* __restrict__ Wqv, const float* __restrict__ Wkv, const float* __restrict__ Wvv,
    unsigned* __restrict__ qs, unsigned* __restrict__ ks, float* __restrict__ vs,
    unsigned* __restrict__ qv, unsigned* __restrict__ kv, float* __restrict__ vv, int n)
{
  __shared__ float stT[64][40];    // transposed s tile (k-major), 16B-aligned cols
  __shared__ float pt[BN][97];     // point staging (x:0..31, y:32..63, z:64..95)
  const int tid = threadIdx.x;
  const int node0 = blockIdx.x * BN;

  #pragma unroll
  for (int r = 0; r < 2; ++r){
    const int idx = tid + r*256;          // float4 index
    const int nd = idx >> 4, c4 = idx & 15;
    const int g = node0 + nd;
    float4 v = make_float4(0.f,0.f,0.f,0.f);
    if (g < n) v = *(const float4*)(s + (size_t)g*64 + c4*4);
    stT[c4*4+0][nd]=v.x; stT[c4*4+1][nd]=v.y; stT[c4*4+2][nd]=v.z; stT[c4*4+3][nd]=v.w;
  }
  __syncthreads();

  const int cg = tid & 63, sl = tid >> 6;
  const int cgp = tid & 31, slp = tid >> 5;
  float acc[8][4];

  pass256(Wqs, stT, cg, sl, acc);
  #pragma unroll
  for (int i=0;i<8;i++){
    const int g = node0 + sl*8 + i;
    if (g < n){
      uint2 u; u.x = pack2(acc[i][0],acc[i][1]); u.y = pack2(acc[i][2],acc[i][3]);
      *(uint2*)(qs + (size_t)g*128 + cg*2) = u;
    }
  }
  pass256(Wks, stT, cg, sl, acc);
  #pragma unroll
  for (int i=0;i<8;i++){
    const int g = node0 + sl*8 + i;
    if (g < n){
      uint2 u; u.x = pack2(acc[i][0],acc[i][1]); u.y = pack2(acc[i][2],acc[i][3]);
      *(uint2*)(ks + (size_t)g*128 + cg*2) = u;
    }
  }
  pass256(Wvs, stT, cg, sl, acc);
  #pragma unroll
  for (int i=0;i<8;i++){
    const int g = node0 + sl*8 + i;
    if (g < n){
      float4 f; f.x=acc[i][0]; f.y=acc[i][1]; f.z=acc[i][2]; f.w=acc[i][3];
      *(float4*)(vs + (size_t)g*256 + cg*4) = f;
    }
  }

  float pac[4][4];

  // q_v: rotate + translate -> bf16
  pass96(Wqv, stT, cgp, slp, pac);
  __syncthreads();
  if (cgp < 24){
    #pragma unroll
    for (int i=0;i<4;i++){
      #pragma unroll
      for (int c=0;c<4;c++) pt[slp*4+i][cgp*4+c] = pac[i][c];
    }
  }
  __syncthreads();
  #pragma unroll
  for (int r = 0; r < 2; ++r){
    const int t2 = tid + r*256;
    const int nd = t2 >> 4, pp = t2 & 15;
    const int g = node0 + nd;
    if (g < n){
      const float4 q4 = *(const float4*)(quat + (size_t)g*4);
      const float tx = trans[(size_t)g*3], ty = trans[(size_t)g*3+1], tz = trans[(size_t)g*3+2];
      float x0,y0,z0,x1,y1,z1;
      quat_rot(q4.x,q4.y,q4.z,q4.w, pt[nd][2*pp],   pt[nd][32+2*pp],   pt[nd][64+2*pp],   x0,y0,z0);
      quat_rot(q4.x,q4.y,q4.z,q4.w, pt[nd][2*pp+1], pt[nd][32+2*pp+1], pt[nd][64+2*pp+1], x1,y1,z1);
      x0+=tx; y0+=ty; z0+=tz; x1+=tx; y1+=ty; z1+=tz;
      unsigned* d = qv + (size_t)g*48 + pp*3;
      d[0] = pack2(x0,y0); d[1] = pack2(z0,x1); d[2] = pack2(y1,z1);
    }
  }

  // k_v: rotate + translate -> bf16
  pass96(Wkv, stT, cgp, slp, pac);
  __syncthreads();
  if (cgp < 24){
    #pragma unroll
    for (int i=0;i<4;i++){
      #pragma unroll
      for (int c=0;c<4;c++) pt[slp*4+i][cgp*4+c] = pac[i][c];
    }
  }
  __syncthreads();
  #pragma unroll
  for (int r = 0; r < 2; ++r){
    const int t2 = tid + r*256;
    const int nd = t2 >> 4, pp = t2 & 15;
    const int g = node0 + nd;
    if (g < n){
      const float4 q4 = *(const float4*)(quat + (size_t)g*4);
      const float tx = trans[(size_t)g*3], ty = trans[(size_t)g*3+1], tz = trans[(size_t)g*3+2];
      float x0,y0,z0,x1,y1,z1;
      quat_rot(q4.x,q4.y,q4.z,q4.w, pt[nd][2*pp],   pt[nd][32+2*pp],   pt[nd][64+2*pp],   x0,y0,z0);
      quat_rot(q4.x,q4.y,q4.z,q4.w, pt[nd][2*pp+1], pt[nd][32+2*pp+1], pt[nd][64+2*pp+1], x1,y1,z1);
      x0+=tx; y0+=ty; z0+=tz; x1+=tx; y1+=ty; z1+=tz;
      unsigned* d = kv + (size_t)g*48 + pp*3;
      d[0] = pack2(x0,y0); d[1] = pack2(z0,x1); d[2] = pack2(y1,z1);
    }
  }

  // v_v: raw (pre-rotation) points == out_vec; f32 PLANE layout
  pass96(Wvv, stT, cgp, slp, pac);
  __syncthreads();
  if (cgp < 24){
    #pragma unroll
    for (int i=0;i<4;i++){
      #pragma unroll
      for (int c=0;c<4;c++) pt[slp*4+i][cgp*4+c] = pac[i][c];
    }
  }
  __syncthreads();
  #pragma unroll
  for (int r = 0; r < 12; ++r){
    const int idx = tid + r*256;
    const int nd = idx / 96, col = idx - nd*96;
    const int g = node0 + nd;
    if (g < n) vv[(size_t)g*96 + col] = pt[nd][col];
  }
}

// ---------------- z projection + CSR fill (k_zf) ---------------------------
// Block = 256 threads = 256 original-order edges.  Single-buffered LDS z tile
// (16.5 KB) + register prefetch of next chunk (T14 async-STAGE).
// Outputs: lg[pos] = bias f32x4 (dense logits array, scattered 16-B store);
//          rec[pos]: uint[16] slot, uses [0:8)=pz bf16x16, [8]=i, [9]=j.

__global__ __launch_bounds__(256) void k_zf(
    const int* __restrict__ ei, const unsigned* __restrict__ rank,
    const unsigned* __restrict__ roff, const float* __restrict__ z,
    const float* __restrict__ Wb,  const float* __restrict__ bb,
    const float* __restrict__ Wdz, const float* __restrict__ bdz,
    float* __restrict__ lg, unsigned* __restrict__ rec, int ne)
{
  __shared__ float zT[16][258];   // one 16-k chunk, transposed, padded
  const int tid = threadIdx.x;
  const int E0  = blockIdx.x * 256;
  const int e   = E0 + tid;
  const bool full = (E0 + 256 <= ne);

  int i = 0, j = 0; unsigned pos = 0;
  if (e < ne){
    i = ei[e]; j = ei[ne + e];
    pos = roff[i] + rank[e];
  }

  float b4[4] = {0.f,0.f,0.f,0.f};
  float pacc[16];
  #pragma unroll
  for (int c=0;c<16;c++) pacc[c]=0.f;

  if (full){
    // prologue: load + stage chunk 0
    float4 rg[4];
    #pragma unroll
    for (int q = 0; q < 4; ++q){
      const int idx = tid + q*256;
      const int row = idx >> 2, f4 = idx & 3;
      rg[q] = *(const float4*)(z + (size_t)(E0+row)*64 + f4*4);
    }
    #pragma unroll
    for (int q = 0; q < 4; ++q){
      const int idx = tid + q*256;
      const int row = idx >> 2, f4 = idx & 3;
      zT[f4*4+0][row]=rg[q].x; zT[f4*4+1][row]=rg[q].y;
      zT[f4*4+2][row]=rg[q].z; zT[f4*4+3][row]=rg[q].w;
    }
    __syncthreads();

    #pragma unroll
    for (int c = 0; c < 4; ++c){
      // issue next chunk's loads BEFORE compute -> latency hides under FMAs
      float4 rn[4];
      if (c < 3){
        #pragma unroll
        for (int q = 0; q < 4; ++q){
          const int idx = tid + q*256;
          const int row = idx >> 2, f4 = idx & 3;
          rn[q] = *(const float4*)(z + (size_t)(E0+row)*64 + (c+1)*16 + f4*4);
        }
      }
      const int kb = c*16;
      #pragma unroll
      for (int kk = 0; kk < 16; ++kk){
        const float zk = zT[kk][tid];
        const int k = kb + kk;
        const float4 wb = *(const float4*)(Wb + k*4);
        b4[0]+=zk*wb.x; b4[1]+=zk*wb.y; b4[2]+=zk*wb.z; b4[3]+=zk*wb.w;
        const float* wd = Wdz + k*16;
        const float4 w0=*(const float4*)(wd),   w1=*(const float4*)(wd+4),
                     w2=*(const float4*)(wd+8), w3=*(const float4*)(wd+12);
        pacc[ 0]+=zk*w0.x; pacc[ 1]+=zk*w0.y; pacc[ 2]+=zk*w0.z; pacc[ 3]+=zk*w0.w;
        pacc[ 4]+=zk*w1.x; pacc[ 5]+=zk*w1.y; pacc[ 6]+=zk*w1.z; pacc[ 7]+=zk*w1.w;
        pacc[ 8]+=zk*w2.x; pacc[ 9]+=zk*w2.y; pacc[10]+=zk*w2.z; pacc[11]+=zk*w2.w;
        pacc[12]+=zk*w3.x; pacc[13]+=zk*w3.y; pacc[14]+=zk*w3.z; pacc[15]+=zk*w3.w;
      }
      __syncthreads();
      if (c < 3){
        #pragma unroll
        for (int q = 0; q < 4; ++q){
          const int idx = tid + q*256;
          const int row = idx >> 2, f4 = idx & 3;
          zT[f4*4+0][row]=rn[q].x; zT[f4*4+1][row]=rn[q].y;
          zT[f4*4+2][row]=rn[q].z; zT[f4*4+3][row]=rn[q].w;
        }
        __syncthreads();
      }
    }
  } else if (e < ne){
    const float* zr = z + (size_t)e*64;
    for (int k4 = 0; k4 < 16; ++k4){
      const float4 zv = *(const float4*)(zr + 4*k4);
      #pragma unroll
      for (int kk = 0; kk < 4; ++kk){
        const int k = 4*k4 + kk;
        const float zk = (kk==0)?zv.x:((kk==1)?zv.y:((kk==2)?zv.z:zv.w));
        const float4 wb = *(const float4*)(Wb + k*4);
        b4[0]+=zk*wb.x; b4[1]+=zk*wb.y; b4[2]+=zk*wb.z; b4[3]+=zk*wb.w;
        const float* wd = Wdz + k*16;
        const float4 w0=*(const float4*)(wd),   w1=*(const float4*)(wd+4),
                     w2=*(const float4*)(wd+8), w3=*(const float4*)(wd+12);
        pacc[ 0]+=zk*w0.x; pacc[ 1]+=zk*w0.y; pacc[ 2]+=zk*w0.z; pacc[ 3]+=zk*w0.w;
        pacc[ 4]+=zk*w1.x; pacc[ 5]+=zk*w1.y; pacc[ 6]+=zk*w1.z; pacc[ 7]+=zk*w1.w;
        pacc[ 8]+=zk*w2.x; pacc[ 9]+=zk*w2.y; pacc[10]+=zk*w2.z; pacc[11]+=zk*w2.w;
        pacc[12]+=zk*w3.x; pacc[13]+=zk*w3.y; pacc[14]+=zk*w3.z; pacc[15]+=zk*w3.w;
      }
    }
  }

  if (e < ne){
    #pragma unroll
    for (int c=0;c<16;c++) pacc[c] += bdz[c];
    uint4 u0, u1;
    u0.x=pack2(pacc[0],pacc[1]);   u0.y=pack2(pacc[2],pacc[3]);
    u0.z=pack2(pacc[4],pacc[5]);   u0.w=pack2(pacc[6],pacc[7]);
    u1.x=pack2(pacc[8],pacc[9]);   u1.y=pack2(pacc[10],pacc[11]);
    u1.z=pack2(pacc[12],pacc[13]); u1.w=pack2(pacc[14],pacc[15]);
    float4 bo;
    bo.x = C_SQRT13*(b4[0] + bb[0]);
    bo.y = C_SQRT13*(b4[1] + bb[1]);
    bo.z = C_SQRT13*(b4[2] + bb[2]);
    bo.w = C_SQRT13*(b4[3] + bb[3]);
    *((float4*)lg + pos) = bo;                  // dense logits array (bias)
    uint4* d = (uint4*)rec + (size_t)pos*4;
    d[0] = u0;
    d[1] = u1;
    d[2] = make_uint4((unsigned)i, (unsigned)j, 0u, 0u);
  }
}

// ------------------------------- edge kernel -------------------------------
// CSR order: consecutive edges share i -> ks[i]/qv[i] L1-resident.  4-lane-
// per-edge split: group g = lane>>2 handles edge el = sb*16+g of its wave,
// lane c = lane&3 reads 16-B slices (4 lanes cover a 64-B line).

__global__ __launch_bounds__(256) void k_edge(
    const float* __restrict__ hwts,
    const unsigned* __restrict__ qs, const unsigned* __restrict__ ks,
    const unsigned* __restrict__ qv, const unsigned* __restrict__ kv,
    const unsigned* __restrict__ rec, float* __restrict__ lg, int ne)
{
  const int tid = threadIdx.x;
  const int P0  = blockIdx.x * 256;
  const int p   = P0 + tid;
  const bool full = (P0 + 256 <= ne);

  // folded softplus head weights (include C_VEC)
  const float hw0 = C_VEC * log1pf(__expf(hwts[0]));
  const float hw1 = C_VEC * log1pf(__expf(hwts[1]));
  const float hw2 = C_VEC * log1pf(__expf(hwts[2]));
  const float hw3 = C_VEC * log1pf(__expf(hwts[3]));

  int i = 0, j = 0;
  float4 bias = make_float4(0.f,0.f,0.f,0.f);
  if (p < ne){
    bias = *((const float4*)lg + p);                         // dense, coalesced
    const uint2 ij = *(const uint2*)(rec + (size_t)p*16 + 8);
    i = (int)ij.x; j = (int)ij.y;
  }

  if (full){
    const int l = tid & 63;
    const int c = l & 3, g = l >> 2;
    #pragma unroll
    for (int sb = 0; sb < 4; ++sb){
      const int el = sb*16 + g;
      const int ie = __shfl(i, el, 64);
      const int je = __shfl(j, el, 64);

      // scalar dot (heads from k-slice index, compile-time per it)
      const uint4* kr = (const uint4*)ks + (size_t)ie*32;
      const uint4* qr = (const uint4*)qs + (size_t)je*32;
      float s0=0.f, s1=0.f, s2=0.f, s3=0.f;
      #pragma unroll
      for (int it = 0; it < 8; ++it){
        const uint4 a = kr[it*4 + c];
        const uint4 b = qr[it*4 + c];
        float d;
        d  = bflo(a.x)*bflo(b.x) + bfhi(a.x)*bfhi(b.x);
        d += bflo(a.y)*bflo(b.y) + bfhi(a.y)*bfhi(b.y);
        d += bflo(a.z)*bflo(b.z) + bfhi(a.z)*bfhi(b.z);
        d += bflo(a.w)*bflo(b.w) + bfhi(a.w)*bfhi(b.w);
        if      (it < 2) s0 += d;
        else if (it < 4) s1 += d;
        else if (it < 6) s2 += d;
        else             s3 += d;
      }

      // vector attention (head = uint4-idx/3; uint4-idx = chunk*4+c)
      const uint4* qvr = (const uint4*)qv + (size_t)ie*12;
      const uint4* kvr = (const uint4*)kv + (size_t)je*12;
      float v0=0.f, v1=0.f, v2=0.f, v3=0.f;
      {
        const uint4 a = qvr[c], b = kvr[c];
        float d, t;
        t = bflo(a.x)-bflo(b.x); d  = t*t;  t = bfhi(a.x)-bfhi(b.x); d += t*t;
        t = bflo(a.y)-bflo(b.y); d += t*t;  t = bfhi(a.y)-bfhi(b.y); d += t*t;
        t = bflo(a.z)-bflo(b.z); d += t*t;  t = bfhi(a.z)-bfhi(b.z); d += t*t;
        t = bflo(a.w)-bflo(b.w); d += t*t;  t = bfhi(a.w)-bfhi(b.w); d += t*t;
        if (c < 3) v0 += d; else v1 += d;
      }
      {
        const uint4 a = qvr[4+c], b = kvr[4+c];
        float d, t;
        t = bflo(a.x)-bflo(b.x); d  = t*t;  t = bfhi(a.x)-bfhi(b.x); d += t*t;
        t = bflo(a.y)-bflo(b.y); d += t*t;  t = bfhi(a.y)-bfhi(b.y); d += t*t;
        t = bflo(a.z)-bflo(b.z); d += t*t;  t = bfhi(a.z)-bfhi(b.z); d += t*t;
        t = bflo(a.w)-bflo(b.w); d += t*t;  t = bfhi(a.w)-bfhi(b.w); d += t*t;
        if (c < 2) v1 += d; else v2 += d;
      }
      {
        const uint4 a = qvr[8+c], b = kvr[8+c];
        float d, t;
        t = bflo(a.x)-bflo(b.x); d  = t*t;  t = bfhi(a.x)-bfhi(b.x); d += t*t;
        t = bflo(a.y)-bflo(b.y); d += t*t;  t = bfhi(a.y)-bfhi(b.y); d += t*t;
        t = bflo(a.z)-bflo(b.z); d += t*t;  t = bfhi(a.z)-bfhi(b.z); d += t*t;
        t = bflo(a.w)-bflo(b.w); d += t*t;  t = bfhi(a.w)-bfhi(b.w); d += t*t;
        if (c < 1) v2 += d; else v3 += d;
      }

      // fold per-head partial logit, reduce across the 4 lanes of the group
      float p0 = C_SQRT83*s0 + hw0*v0;
      float p1 = C_SQRT83*s1 + hw1*v1;
      float p2 = C_SQRT83*s2 + hw2*v2;
      float p3 = C_SQRT83*s3 + hw3*v3;
      #pragma unroll
      for (int msk = 1; msk < 4; msk <<= 1){
        p0 += __shfl_xor(p0, msk, 64);
        p1 += __shfl_xor(p1, msk, 64);
        p2 += __shfl_xor(p2, msk, 64);
        p3 += __shfl_xor(p3, msk, 64);
      }
      const float pc = (c==0)?p0:((c==1)?p1:((c==2)?p2:p3));

      // route the 4 head-logits back to the owning lane (owners: l>>4 == sb)
      const int srcbase = (l & 15) << 2;
      const float q0 = __shfl(pc, srcbase+0, 64);
      const float q1 = __shfl(pc, srcbase+1, 64);
      const float q2 = __shfl(pc, srcbase+2, 64);
      const float q3 = __shfl(pc, srcbase+3, 64);
      if ((l >> 4) == sb){
        float4 lgv; lgv.x = q0 + bias.x; lgv.y = q1 + bias.y;
        lgv.z = q2 + bias.z; lgv.w = q3 + bias.w;
        *((float4*)lg + p) = lgv;                            // dense, coalesced
      }
    }
  } else if (p < ne){
    // tail block: per-thread gather (never hit when ne % 256 == 0)
    const uint4* kr = (const uint4*)ks + (size_t)i*32;
    const uint4* qr = (const uint4*)qs + (size_t)j*32;
    float sdot[4];
    #pragma unroll
    for (int h = 0; h < 4; ++h){
      float acc = 0.f;
      #pragma unroll
      for (int cc = 0; cc < 8; ++cc){
        const uint4 a = kr[h*8+cc];
        const uint4 b = qr[h*8+cc];
        acc += bflo(a.x)*bflo(b.x) + bfhi(a.x)*bfhi(b.x);
        acc += bflo(a.y)*bflo(b.y) + bfhi(a.y)*bfhi(b.y);
        acc += bflo(a.z)*bflo(b.z) + bfhi(a.z)*bfhi(b.z);
        acc += bflo(a.w)*bflo(b.w) + bfhi(a.w)*bfhi(b.w);
      }
      sdot[h] = acc;
    }
    const uint4* qvr = (const uint4*)qv + (size_t)i*12;
    const uint4* kvr = (const uint4*)kv + (size_t)j*12;
    float vsum[4];
    #pragma unroll
    for (int h = 0; h < 4; ++h){
      float acc = 0.f;
      #pragma unroll
      for (int cc = 0; cc < 3; ++cc){
        const uint4 a = qvr[h*3+cc];
        const uint4 b = kvr[h*3+cc];
        float d;
        d = bflo(a.x)-bflo(b.x); acc += d*d;  d = bfhi(a.x)-bfhi(b.x); acc += d*d;
        d = bflo(a.y)-bflo(b.y); acc += d*d;  d = bfhi(a.y)-bfhi(b.y); acc += d*d;
        d = bflo(a.z)-bflo(b.z); acc += d*d;  d = bfhi(a.z)-bfhi(b.z); acc += d*d;
        d = bflo(a.w)-bflo(b.w); acc += d*d;  d = bfhi(a.w)-bfhi(b.w); acc += d*d;
      }
      vsum[h] = acc;
    }
    float4 lgv;
    lgv.x = C_SQRT83*sdot[0] + bias.x + hw0*vsum[0];
    lgv.y = C_SQRT83*sdot[1] + bias.y + hw1*vsum[1];
    lgv.z = C_SQRT83*sdot[2] + bias.z + hw2*vsum[2];
    lgv.w = C_SQRT83*sdot[3] + bias.w + hw3*vsum[3];
    *((float4*)lg + p) = lgv;
  }
}

// ----------------------- wave-per-node softmax + pair -----------------------
// lg: dense E x float4 logits (coalesced stream).  rec: pz at [0:8), i,j at [8,9].

__global__ __launch_bounds__(256) void k_soft(
    const float* __restrict__ lg, const unsigned* __restrict__ rec,
    const unsigned* __restrict__ row_off, float* __restrict__ out_pair, int n)
{
  const int node = blockIdx.x*4 + (threadIdx.x >> 6);
  if (node >= n) return;
  const int lane = threadIdx.x & 63;
  const int beg = (int)row_off[node], end = (int)row_off[node+1];
  const float4* lg4 = (const float4*)lg;

  // ---- phase 1: per-head max and sum (lane-parallel over edges) ----
  float m[4] = {-3.0e38f,-3.0e38f,-3.0e38f,-3.0e38f};
  for (int p = beg + lane; p < end; p += 64){
    const float4 l = lg4[p];
    m[0]=fmaxf(m[0],l.x); m[1]=fmaxf(m[1],l.y); m[2]=fmaxf(m[2],l.z); m[3]=fmaxf(m[3],l.w);
  }
  #pragma unroll
  for (int msk = 1; msk < 64; msk <<= 1){
    #pragma unroll
    for (int h=0;h<4;h++) m[h] = fmaxf(m[h], __shfl_xor(m[h], msk));
  }
  float S[4] = {0.f,0.f,0.f,0.f};
  for (int p = beg + lane; p < end; p += 64){
    const float4 l = lg4[p];
    S[0]+=__expf(l.x-m[0]); S[1]+=__expf(l.y-m[1]);
    S[2]+=__expf(l.z-m[2]); S[3]+=__expf(l.w-m[3]);
  }
  #pragma unroll
  for (int msk = 1; msk < 64; msk <<= 1){
    #pragma unroll
    for (int h=0;h<4;h++) S[h] += __shfl_xor(S[h], msk);
  }
  float inv[4];
  #pragma unroll
  for (int h=0;h<4;h++) inv[h] = (S[h] > 0.f) ? (1.f/S[h]) : 0.f;

  // ---- phase 2: weighted pair aggregation ----
  const int e4 = lane >> 4, c = lane & 15;
  float acc[4] = {0.f,0.f,0.f,0.f};
  for (int base = beg; base < end; base += 4){
    const int p = base + e4;
    if (p < end){
      const float4 l = lg4[p];
      const unsigned u = rec[(size_t)p*16 + (c>>1)];
      const float pzv = (c & 1) ? bfhi(u) : bflo(u);
      acc[0] += __expf(l.x-m[0]) * pzv;
      acc[1] += __expf(l.y-m[1]) * pzv;
      acc[2] += __expf(l.z-m[2]) * pzv;
      acc[3] += __expf(l.w-m[3]) * pzv;
    }
  }
  #pragma unroll
  for (int msk = 16; msk < 64; msk <<= 1){
    #pragma unroll
    for (int h=0;h<4;h++) acc[h] += __shfl_xor(acc[h], msk);
  }
  const int hOut = lane >> 4;          // output layout: [h*16 + c]
  out_pair[(size_t)node*64 + lane] = acc[hOut] * inv[hOut];
}

// --------------------- feats assembly + output GEMM ------------------------
// 16 nodes/block: 28.7 KB LDS -> 5 blocks/CU (fixes 13% occupancy wall).

#define BNO 16

__global__ __launch_bounds__(256) void k_out(
    const float* __restrict__ vs, const float* __restrict__ vv,
    const float* __restrict__ out_pair, const unsigned* __restrict__ row_off,
    const float* __restrict__ quat, const float* __restrict__ trans,
    const float* __restrict__ Wout, const float* __restrict__ bout,
    float* __restrict__ out, int n)
{
  __shared__ float feats[BNO][448];
  __shared__ int degs[BNO];
  const int tid = threadIdx.x;
  const int node0 = blockIdx.x*BNO;

  if (tid < BNO){
    const int g = node0 + tid;
    degs[tid] = (g < n) ? (int)(row_off[g+1] - row_off[g]) : 1;
  }
  __syncthreads();

  for (int x = tid; x < BNO*256; x += 256){
    const int nd = x >> 8, c = x & 255;
    const int g = node0 + nd;
    feats[nd][c] = (g < n && degs[nd] > 0) ? vs[(size_t)g*256 + c] : 0.f;
  }
  for (int x = tid; x < BNO*64; x += 256){
    const int nd = x >> 6, c = x & 63;
    const int g = node0 + nd;
    feats[nd][384 + c] = (g < n) ? out_pair[(size_t)g*64 + c] : 0.f;
  }
  for (int x = tid; x < BNO*32; x += 256){
    const int nd = x >> 5, pt = x & 31;
    const int g = node0 + nd;
    float X=0.f, Y=0.f, Z=0.f;
    if (g < n){
      if (degs[nd] > 0){
        X = vv[(size_t)g*96 + pt];
        Y = vv[(size_t)g*96 + 32 + pt];
        Z = vv[(size_t)g*96 + 64 + pt];
      } else {
        const float4 q4 = *(const float4*)(quat + (size_t)g*4);
        const float tx = trans[(size_t)g*3], ty = trans[(size_t)g*3+1], tz = trans[(size_t)g*3+2];
        quat_rot(q4.x, -q4.y, -q4.z, -q4.w, -tx, -ty, -tz, X, Y, Z);
      }
    }
    feats[nd][256 + pt] = X;
    feats[nd][288 + pt] = Y;
    feats[nd][320 + pt] = Z;
    feats[nd][352 + pt] = sqrtf(X*X + Y*Y + Z*Z + 1e-8f);
  }
  __syncthreads();

  const int lane = tid & 63;
  const int wave = tid >> 6;
  float acc[4];
  #pragma unroll
  for (int q4=0;q4<4;q4++) acc[q4]=0.f;

  for (int k0 = 0; k0 < 448; k0 += 4){
    const float w0 = Wout[(size_t)(k0+0)*64 + lane];
    const float w1 = Wout[(size_t)(k0+1)*64 + lane];
    const float w2 = Wout[(size_t)(k0+2)*64 + lane];
    const float w3 = Wout[(size_t)(k0+3)*64 + lane];
    #pragma unroll
    for (int q4 = 0; q4 < 4; ++q4){
      const float4 f = *(const float4*)&feats[wave*4 + q4][k0];
      acc[q4] += f.x*w0 + f.y*w1 + f.z*w2 + f.w*w3;
    }
  }
  const float bo = bout[lane];
  #pragma unroll
  for (int q4 = 0; q4 < 4; ++q4){
    const int g = node0 + wave*4 + q4;
    if (g < n) out[(size_t)g*64 + lane] = acc[q4] + bo;
  }
}

// --------------------------------- launch ----------------------------------

extern "C" void kernel_launch(void* const* d_in, const int* in_sizes, int n_in,
                              void* d_out, int out_size, void* d_ws, size_t ws_size,
                              hipStream_t stream) {
  const float* s     = (const float*)d_in[0];
  const float* z     = (const float*)d_in[1];
  const int*   ei    = (const int*)  d_in[2];
  const float* quat  = (const float*)d_in[3];
  const float* trans = (const float*)d_in[4];
  const float* Wqs   = (const float*)d_in[5];
  const float* Wks   = (const float*)d_in[6];
  const float* Wvs   = (const float*)d_in[7];
  const float* Wqv   = (const float*)d_in[8];
  const float* Wkv   = (const float*)d_in[9];
  const float* Wvv   = (const float*)d_in[10];
  const float* Wb    = (const float*)d_in[11];
  const float* bb    = (const float*)d_in[12];
  const float* Wdz   = (const float*)d_in[13];
  const float* bdz   = (const float*)d_in[14];
  const float* hwts  = (const float*)d_in[15];
  const float* Wout  = (const float*)d_in[16];
  const float* bout  = (const float*)d_in[17];
  float* out = (float*)d_out;

  const int n  = in_sizes[0] / 64;   // 20000
  const int ne = in_sizes[1] / 64;   // 640000

  size_t off = 0;
  char* base = (char*)d_ws;
  auto take = [&](size_t bytes)->char* {
    char* p = base + off;
    off += (bytes + 255) & ~(size_t)255;
    return p;
  };
  unsigned* qs     = (unsigned*)take((size_t)n*512);    // bf16 N x 256
  unsigned* ks     = (unsigned*)take((size_t)n*512);    // bf16 N x 256
  unsigned* qvt    = (unsigned*)take((size_t)n*192);    // bf16 N x 96 (rot + t)
  unsigned* kvt    = (unsigned*)take((size_t)n*192);    // bf16 N x 96 (rot + t)
  float*    vs     = (float*)   take((size_t)n*1024);   // f32  N x 256
  float*    vv     = (float*)   take((size_t)n*384);    // f32  N x 96 (raw, planes)
  float*    lg     = (float*)   take((size_t)ne*16);    // f32  E x 4 dense logits
  unsigned* rec    = (unsigned*)take((size_t)ne*64);    // 64-B record per edge
  unsigned* counts = (unsigned*)take((size_t)n*4);
  unsigned* roff   = (unsigned*)take((size_t)(n+1)*4);
  unsigned* rank   = (unsigned*)take((size_t)ne*4);
  float*    opair  = (float*)   take((size_t)n*256);    // f32  N x 64
  (void)ws_size; (void)n_in; (void)out_size;

  const int gbE = (ne + 255) / 256;

  hipMemsetAsync(counts, 0, (size_t)n*4, stream);
  k_count<<<gbE, 256, 0, stream>>>(ei, counts, rank, ne);
  k_scan <<<1,   256, 0, stream>>>(counts, roff, n);
  k_proj <<<(n + BN - 1)/BN, 256, 0, stream>>>(s, quat, trans, Wqs, Wks, Wvs, Wqv, Wkv, Wvv,
                                               qs, ks, vs, qvt, kvt, vv, n);
  k_zf   <<<gbE, 256, 0, stream>>>(ei, rank, roff, z, Wb, bb, Wdz, bdz, lg, rec, ne);
  k_edge <<<gbE, 256, 0, stream>>>(hwts, qs, ks, qvt, kvt, rec, lg, ne);
  k_soft <<<(n + 3)/4, 256, 0, stream>>>(lg, rec, roff, opair, n);
  k_out  <<<(n + BNO - 1)/BNO, 256, 0, stream>>>(vs, vv, opair, roff, quat, trans,
                                                 Wout, bout, out, n);
}

// Round 6
// 565.163 us; speedup vs baseline: 1.2423x; 1.0457x over previous
//
#include <hip/hip_runtime.h>
#include <stdint.h>

// ---------------------------------------------------------------------------
// InvariantPointAttention, N=20000 nodes, E=640000 edges, H=4, S=64, QK=VD=8
//
// Pipeline (all on `stream`):
//   memset(counts) / k_count / k_scan : CSR build.  k_count stores rank[e]
//       (atomic return).
//   k_proj   : tiled per-node projections (32 nodes/block, transposed LDS
//              s-tile): q_s,k_s (bf16 Nx256), q_v,k_v (rot+trans bf16 Nx96),
//              v_s (f32 Nx256), v_loc (raw points f32 Nx96, PLANE layout).
//   k_zf     : per ORIGINAL edge e (coalesced z stream via single-buffered
//              16.5 KB LDS transpose tile + register prefetch of the next
//              chunk): z@Wb -> bias, z@Wdz -> pz; ONE 64-B record
//              {bias f32x4, pz bf16x16, i, j} scattered to CSR pos as a
//              single 4x-uint4 line burst (round-5's split write was a 19 MB
//              write-amplification regression).
//   k_edge   : per CSR edge.  bias+ij read from rec (coalesced); 4-lane-per-
//              edge split gathers (16 lines/instr); final logits written to
//              DENSE lg[p] (coalesced).  No LDS -> high occupancy.
//   k_soft   : wave-per-node, register/shuffle only softmax + pair
//              aggregation; phase 1 streams DENSE lg (fully coalesced).
//   k_out    : 16 nodes/block (28.7 KB LDS -> 5 blocks/CU): feats[448] +
//              feats @ Wout + bout.
// ---------------------------------------------------------------------------

#define C_SQRT83  1.6329931618554518f   // sqrt(8/3)
#define C_SQRT13  0.5773502691896258f   // sqrt(1/3)
#define C_VEC    -0.04811252243246881f  // -0.5*sqrt(1/108)

__device__ __forceinline__ unsigned short f2bf(float f){
  unsigned u = __float_as_uint(f);
  u += 0x7fffu + ((u >> 16) & 1u);          // round-to-nearest-even
  return (unsigned short)(u >> 16);
}
__device__ __forceinline__ unsigned pack2(float a, float b){
  return (unsigned)f2bf(a) | ((unsigned)f2bf(b) << 16);
}
__device__ __forceinline__ float bflo(unsigned u){ return __uint_as_float(u << 16); }
__device__ __forceinline__ float bfhi(unsigned u){ return __uint_as_float(u & 0xffff0000u); }

__device__ __forceinline__ void quat_rot(float w, float ux, float uy, float uz,
                                         float vx, float vy, float vz,
                                         float& ox, float& oy, float& oz){
  float cx = uy*vz - uz*vy;
  float cy = uz*vx - ux*vz;
  float cz = ux*vy - uy*vx;
  float dx = uy*cz - uz*cy;
  float dy = uz*cx - ux*cz;
  float dz = ux*cy - uy*cx;
  ox = vx + 2.f*(w*cx + dx);
  oy = vy + 2.f*(w*cy + dy);
  oz = vz + 2.f*(w*cz + dz);
}

// -------------------------------- CSR build --------------------------------

__global__ __launch_bounds__(256) void k_count(const int* __restrict__ ei,
                                               unsigned* __restrict__ counts,
                                               unsigned* __restrict__ rank, int ne){
  int e = blockIdx.x*256 + threadIdx.x;
  if (e >= ne) return;
  rank[e] = atomicAdd(&counts[ei[e]], 1u);
}

__global__ __launch_bounds__(256) void k_scan(const unsigned* __restrict__ counts,
                                              unsigned* __restrict__ row_off, int n){
  __shared__ unsigned part[256];
  int t = threadIdx.x;
  int chunk = (n + 255) >> 8;
  int s0 = t*chunk, s1 = min(s0 + chunk, n);
  unsigned sum = 0;
  for (int k = s0; k < s1; ++k) sum += counts[k];
  part[t] = sum; __syncthreads();
  for (int off = 1; off < 256; off <<= 1){
    unsigned v = (t >= off) ? part[t-off] : 0u;
    __syncthreads();
    part[t] += v;
    __syncthreads();
  }
  unsigned run = (t == 0) ? 0u : part[t-1];
  for (int k = s0; k < s1; ++k){
    row_off[k] = run; run += counts[k];
  }
  if (t == 255) row_off[n] = part[255];
}

// ------------------------------ node projections ----------------------------
// Block = 32 nodes, 256 threads.  s tile TRANSPOSED in LDS: stT[k][node].

#define BN 32

__device__ __forceinline__ void pass256(const float* __restrict__ W,
                                        const float stT[64][40], int cg, int sl,
                                        float acc[8][4]){
  #pragma unroll
  for (int i=0;i<8;i++){ acc[i][0]=0.f; acc[i][1]=0.f; acc[i][2]=0.f; acc[i][3]=0.f; }
  #pragma unroll 4
  for (int k = 0; k < 64; ++k){
    const float4 w  = *(const float4*)(W + (size_t)k*256 + cg*4);
    const float4 n0 = *(const float4*)&stT[k][sl*8];
    const float4 n1 = *(const float4*)&stT[k][sl*8+4];
    acc[0][0]+=n0.x*w.x; acc[0][1]+=n0.x*w.y; acc[0][2]+=n0.x*w.z; acc[0][3]+=n0.x*w.w;
    acc[1][0]+=n0.y*w.x; acc[1][1]+=n0.y*w.y; acc[1][2]+=n0.y*w.z; acc[1][3]+=n0.y*w.w;
    acc[2][0]+=n0.z*w.x; acc[2][1]+=n0.z*w.y; acc[2][2]+=n0.z*w.z; acc[2][3]+=n0.z*w.w;
    acc[3][0]+=n0.w*w.x; acc[3][1]+=n0.w*w.y; acc[3][2]+=n0.w*w.z; acc[3][3]+=n0.w*w.w;
    acc[4][0]+=n1.x*w.x; acc[4][1]+=n1.x*w.y; acc[4][2]+=n1.x*w.z; acc[4][3]+=n1.x*w.w;
    acc[5][0]+=n1.y*w.x; acc[5][1]+=n1.y*w.y; acc[5][2]+=n1.y*w.z; acc[5][3]+=n1.y*w.w;
    acc[6][0]+=n1.z*w.x; acc[6][1]+=n1.z*w.y; acc[6][2]+=n1.z*w.z; acc[6][3]+=n1.z*w.w;
    acc[7][0]+=n1.w*w.x; acc[7][1]+=n1.w*w.y; acc[7][2]+=n1.w*w.z; acc[7][3]+=n1.w*w.w;
  }
}

__device__ __forceinline__ void pass96(const float* __restrict__ W,
                                       const float stT[64][40], int cgp, int slp,
                                       float acc[4][4]){
  #pragma unroll
  for (int i=0;i<4;i++){ acc[i][0]=0.f; acc[i][1]=0.f; acc[i][2]=0.f; acc[i][3]=0.f; }
  if (cgp >= 24) return;
  #pragma unroll 4
  for (int k = 0; k < 64; ++k){
    const float4 w = *(const float4*)(W + (size_t)k*96 + cgp*4);
    const float4 nv = *(const float4*)&stT[k][slp*4];
    acc[0][0]+=nv.x*w.x; acc[0][1]+=nv.x*w.y; acc[0][2]+=nv.x*w.z; acc[0][3]+=nv.x*w.w;
    acc[1][0]+=nv.y*w.x; acc[1][1]+=nv.y*w.y; acc[1][2]+=nv.y*w.z; acc[1][3]+=nv.y*w.w;
    acc[2][0]+=nv.z*w.x; acc[2][1]+=nv.z*w.y; acc[2][2]+=nv.z*w.z; acc[2][3]+=nv.z*w.w;
    acc[3][0]+=nv.w*w.x; acc[3][1]+=nv.w*w.y; acc[3][2]+=nv.w*w.z; acc[3][3]+=nv.w*w.w;
  }
}

__global__ __launch_bounds__(256) void k_proj(
    const float* __restrict__ s, const float* __restrict__ quat, const float* __restrict__ trans,
    const float* __restrict__ Wqs, const float* __restrict__ Wks, const float* __restrict__ Wvs,
    const float* __restrict__ Wqv, const float* __restrict__ Wkv, const float* __restrict__ Wvv,
    unsigned* __restrict__ qs, unsigned* __restrict__ ks, float* __restrict__ vs,
    unsigned* __restrict__ qv, unsigned* __restrict__ kv, float* __restrict__ vv, int n)
{
  __shared__ float stT[64][40];    // transposed s tile (k-major), 16B-aligned cols
  __shared__ float pt[BN][97];     // point staging (x:0..31, y:32..63, z:64..95)
  const int tid = threadIdx.x;
  const int node0 = blockIdx.x * BN;

  #pragma unroll
  for (int r = 0; r < 2; ++r){
    const int idx = tid + r*256;          // float4 index
    const int nd = idx >> 4, c4 = idx & 15;
    const int g = node0 + nd;
    float4 v = make_float4(0.f,0.f,0.f,0.f);
    if (g < n) v = *(const float4*)(s + (size_t)g*64 + c4*4);
    stT[c4*4+0][nd]=v.x; stT[c4*4+1][nd]=v.y; stT[c4*4+2][nd]=v.z; stT[c4*4+3][nd]=v.w;
  }
  __syncthreads();

  const int cg = tid & 63, sl = tid >> 6;
  const int cgp = tid & 31, slp = tid >> 5;
  float acc[8][4];

  pass256(Wqs, stT, cg, sl, acc);
  #pragma unroll
  for (int i=0;i<8;i++){
    const int g = node0 + sl*8 + i;
    if (g < n){
      uint2 u; u.x = pack2(acc[i][0],acc[i][1]); u.y = pack2(acc[i][2],acc[i][3]);
      *(uint2*)(qs + (size_t)g*128 + cg*2) = u;
    }
  }
  pass256(Wks, stT, cg, sl, acc);
  #pragma unroll
  for (int i=0;i<8;i++){
    const int g = node0 + sl*8 + i;
    if (g < n){
      uint2 u; u.x = pack2(acc[i][0],acc[i][1]); u.y = pack2(acc[i][2],acc[i][3]);
      *(uint2*)(ks + (size_t)g*128 + cg*2) = u;
    }
  }
  pass256(Wvs, stT, cg, sl, acc);
  #pragma unroll
  for (int i=0;i<8;i++){
    const int g = node0 + sl*8 + i;
    if (g < n){
      float4 f; f.x=acc[i][0]; f.y=acc[i][1]; f.z=acc[i][2]; f.w=acc[i][3];
      *(float4*)(vs + (size_t)g*256 + cg*4) = f;
    }
  }

  float pac[4][4];

  // q_v: rotate + translate -> bf16
  pass96(Wqv, stT, cgp, slp, pac);
  __syncthreads();
  if (cgp < 24){
    #pragma unroll
    for (int i=0;i<4;i++){
      #pragma unroll
      for (int c=0;c<4;c++) pt[slp*4+i][cgp*4+c] = pac[i][c];
    }
  }
  __syncthreads();
  #pragma unroll
  for (int r = 0; r < 2; ++r){
    const int t2 = tid + r*256;
    const int nd = t2 >> 4, pp = t2 & 15;
    const int g = node0 + nd;
    if (g < n){
      const float4 q4 = *(const float4*)(quat + (size_t)g*4);
      const float tx = trans[(size_t)g*3], ty = trans[(size_t)g*3+1], tz = trans[(size_t)g*3+2];
      float x0,y0,z0,x1,y1,z1;
      quat_rot(q4.x,q4.y,q4.z,q4.w, pt[nd][2*pp],   pt[nd][32+2*pp],   pt[nd][64+2*pp],   x0,y0,z0);
      quat_rot(q4.x,q4.y,q4.z,q4.w, pt[nd][2*pp+1], pt[nd][32+2*pp+1], pt[nd][64+2*pp+1], x1,y1,z1);
      x0+=tx; y0+=ty; z0+=tz; x1+=tx; y1+=ty; z1+=tz;
      unsigned* d = qv + (size_t)g*48 + pp*3;
      d[0] = pack2(x0,y0); d[1] = pack2(z0,x1); d[2] = pack2(y1,z1);
    }
  }

  // k_v: rotate + translate -> bf16
  pass96(Wkv, stT, cgp, slp, pac);
  __syncthreads();
  if (cgp < 24){
    #pragma unroll
    for (int i=0;i<4;i++){
      #pragma unroll
      for (int c=0;c<4;c++) pt[slp*4+i][cgp*4+c] = pac[i][c];
    }
  }
  __syncthreads();
  #pragma unroll
  for (int r = 0; r < 2; ++r){
    const int t2 = tid + r*256;
    const int nd = t2 >> 4, pp = t2 & 15;
    const int g = node0 + nd;
    if (g < n){
      const float4 q4 = *(const float4*)(quat + (size_t)g*4);
      const float tx = trans[(size_t)g*3], ty = trans[(size_t)g*3+1], tz = trans[(size_t)g*3+2];
      float x0,y0,z0,x1,y1,z1;
      quat_rot(q4.x,q4.y,q4.z,q4.w, pt[nd][2*pp],   pt[nd][32+2*pp],   pt[nd][64+2*pp],   x0,y0,z0);
      quat_rot(q4.x,q4.y,q4.z,q4.w, pt[nd][2*pp+1], pt[nd][32+2*pp+1], pt[nd][64+2*pp+1], x1,y1,z1);
      x0+=tx; y0+=ty; z0+=tz; x1+=tx; y1+=ty; z1+=tz;
      unsigned* d = kv + (size_t)g*48 + pp*3;
      d[0] = pack2(x0,y0); d[1] = pack2(z0,x1); d[2] = pack2(y1,z1);
    }
  }

  // v_v: raw (pre-rotation) points == out_vec; f32 PLANE layout
  pass96(Wvv, stT, cgp, slp, pac);
  __syncthreads();
  if (cgp < 24){
    #pragma unroll
    for (int i=0;i<4;i++){
      #pragma unroll
      for (int c=0;c<4;c++) pt[slp*4+i][cgp*4+c] = pac[i][c];
    }
  }
  __syncthreads();
  #pragma unroll
  for (int r = 0; r < 12; ++r){
    const int idx = tid + r*256;
    const int nd = idx / 96, col = idx - nd*96;
    const int g = node0 + nd;
    if (g < n) vv[(size_t)g*96 + col] = pt[nd][col];
  }
}

// ---------------- z projection + CSR fill (k_zf) ---------------------------
// Block = 256 threads = 256 original-order edges.  Single-buffered LDS z tile
// (16.5 KB) + register prefetch of next chunk (T14 async-STAGE).
// ONE 64-B record per edge at CSR pos (16 uints):
//   [0:4) bias f32x4 | [4:12) pz bf16x16 | [12] i | [13] j | [14:16) pad

__global__ __launch_bounds__(256) void k_zf(
    const int* __restrict__ ei, const unsigned* __restrict__ rank,
    const unsigned* __restrict__ roff, const float* __restrict__ z,
    const float* __restrict__ Wb,  const float* __restrict__ bb,
    const float* __restrict__ Wdz, const float* __restrict__ bdz,
    unsigned* __restrict__ rec, int ne)
{
  __shared__ float zT[16][258];   // one 16-k chunk, transposed, padded
  const int tid = threadIdx.x;
  const int E0  = blockIdx.x * 256;
  const int e   = E0 + tid;
  const bool full = (E0 + 256 <= ne);

  int i = 0, j = 0; unsigned pos = 0;
  if (e < ne){
    i = ei[e]; j = ei[ne + e];
    pos = roff[i] + rank[e];
  }

  float b4[4] = {0.f,0.f,0.f,0.f};
  float pacc[16];
  #pragma unroll
  for (int c=0;c<16;c++) pacc[c]=0.f;

  if (full){
    // prologue: load + stage chunk 0
    float4 rg[4];
    #pragma unroll
    for (int q = 0; q < 4; ++q){
      const int idx = tid + q*256;
      const int row = idx >> 2, f4 = idx & 3;
      rg[q] = *(const float4*)(z + (size_t)(E0+row)*64 + f4*4);
    }
    #pragma unroll
    for (int q = 0; q < 4; ++q){
      const int idx = tid + q*256;
      const int row = idx >> 2, f4 = idx & 3;
      zT[f4*4+0][row]=rg[q].x; zT[f4*4+1][row]=rg[q].y;
      zT[f4*4+2][row]=rg[q].z; zT[f4*4+3][row]=rg[q].w;
    }
    __syncthreads();

    #pragma unroll
    for (int c = 0; c < 4; ++c){
      // issue next chunk's loads BEFORE compute -> latency hides under FMAs
      float4 rn[4];
      if (c < 3){
        #pragma unroll
        for (int q = 0; q < 4; ++q){
          const int idx = tid + q*256;
          const int row = idx >> 2, f4 = idx & 3;
          rn[q] = *(const float4*)(z + (size_t)(E0+row)*64 + (c+1)*16 + f4*4);
        }
      }
      const int kb = c*16;
      #pragma unroll
      for (int kk = 0; kk < 16; ++kk){
        const float zk = zT[kk][tid];
        const int k = kb + kk;
        const float4 wb = *(const float4*)(Wb + k*4);
        b4[0]+=zk*wb.x; b4[1]+=zk*wb.y; b4[2]+=zk*wb.z; b4[3]+=zk*wb.w;
        const float* wd = Wdz + k*16;
        const float4 w0=*(const float4*)(wd),   w1=*(const float4*)(wd+4),
                     w2=*(const float4*)(wd+8), w3=*(const float4*)(wd+12);
        pacc[ 0]+=zk*w0.x; pacc[ 1]+=zk*w0.y; pacc[ 2]+=zk*w0.z; pacc[ 3]+=zk*w0.w;
        pacc[ 4]+=zk*w1.x; pacc[ 5]+=zk*w1.y; pacc[ 6]+=zk*w1.z; pacc[ 7]+=zk*w1.w;
        pacc[ 8]+=zk*w2.x; pacc[ 9]+=zk*w2.y; pacc[10]+=zk*w2.z; pacc[11]+=zk*w2.w;
        pacc[12]+=zk*w3.x; pacc[13]+=zk*w3.y; pacc[14]+=zk*w3.z; pacc[15]+=zk*w3.w;
      }
      __syncthreads();
      if (c < 3){
        #pragma unroll
        for (int q = 0; q < 4; ++q){
          const int idx = tid + q*256;
          const int row = idx >> 2, f4 = idx & 3;
          zT[f4*4+0][row]=rn[q].x; zT[f4*4+1][row]=rn[q].y;
          zT[f4*4+2][row]=rn[q].z; zT[f4*4+3][row]=rn[q].w;
        }
        __syncthreads();
      }
    }
  } else if (e < ne){
    const float* zr = z + (size_t)e*64;
    for (int k4 = 0; k4 < 16; ++k4){
      const float4 zv = *(const float4*)(zr + 4*k4);
      #pragma unroll
      for (int kk = 0; kk < 4; ++kk){
        const int k = 4*k4 + kk;
        const float zk = (kk==0)?zv.x:((kk==1)?zv.y:((kk==2)?zv.z:zv.w));
        const float4 wb = *(const float4*)(Wb + k*4);
        b4[0]+=zk*wb.x; b4[1]+=zk*wb.y; b4[2]+=zk*wb.z; b4[3]+=zk*wb.w;
        const float* wd = Wdz + k*16;
        const float4 w0=*(const float4*)(wd),   w1=*(const float4*)(wd+4),
                     w2=*(const float4*)(wd+8), w3=*(const float4*)(wd+12);
        pacc[ 0]+=zk*w0.x; pacc[ 1]+=zk*w0.y; pacc[ 2]+=zk*w0.z; pacc[ 3]+=zk*w0.w;
        pacc[ 4]+=zk*w1.x; pacc[ 5]+=zk*w1.y; pacc[ 6]+=zk*w1.z; pacc[ 7]+=zk*w1.w;
        pacc[ 8]+=zk*w2.x; pacc[ 9]+=zk*w2.y; pacc[10]+=zk*w2.z; pacc[11]+=zk*w2.w;
        pacc[12]+=zk*w3.x; pacc[13]+=zk*w3.y; pacc[14]+=zk*w3.z; pacc[15]+=zk*w3.w;
      }
    }
  }

  if (e < ne){
    #pragma unroll
    for (int c=0;c<16;c++) pacc[c] += bdz[c];
    uint4 u0, u1;
    u0.x=pack2(pacc[0],pacc[1]);   u0.y=pack2(pacc[2],pacc[3]);
    u0.z=pack2(pacc[4],pacc[5]);   u0.w=pack2(pacc[6],pacc[7]);
    u1.x=pack2(pacc[8],pacc[9]);   u1.y=pack2(pacc[10],pacc[11]);
    u1.z=pack2(pacc[12],pacc[13]); u1.w=pack2(pacc[14],pacc[15]);
    float4 bo;
    bo.x = C_SQRT13*(b4[0] + bb[0]);
    bo.y = C_SQRT13*(b4[1] + bb[1]);
    bo.z = C_SQRT13*(b4[2] + bb[2]);
    bo.w = C_SQRT13*(b4[3] + bb[3]);
    uint4* d = (uint4*)rec + (size_t)pos*4;     // one 64-B line burst
    d[0] = *(uint4*)&bo;
    d[1] = u0;
    d[2] = u1;
    d[3] = make_uint4((unsigned)i, (unsigned)j, 0u, 0u);
  }
}

// ------------------------------- edge kernel -------------------------------
// CSR order: consecutive edges share i -> ks[i]/qv[i] L1-resident.  4-lane-
// per-edge split: group g = lane>>2 handles edge el = sb*16+g of its wave,
// lane c = lane&3 reads 16-B slices (4 lanes cover a 64-B line).
// bias+ij from rec (coalesced); final logits -> DENSE lg (coalesced).

__global__ __launch_bounds__(256) void k_edge(
    const float* __restrict__ hwts,
    const unsigned* __restrict__ qs, const unsigned* __restrict__ ks,
    const unsigned* __restrict__ qv, const unsigned* __restrict__ kv,
    const unsigned* __restrict__ rec, float* __restrict__ lg, int ne)
{
  const int tid = threadIdx.x;
  const int P0  = blockIdx.x * 256;
  const int p   = P0 + tid;
  const bool full = (P0 + 256 <= ne);

  // folded softplus head weights (include C_VEC)
  const float hw0 = C_VEC * log1pf(__expf(hwts[0]));
  const float hw1 = C_VEC * log1pf(__expf(hwts[1]));
  const float hw2 = C_VEC * log1pf(__expf(hwts[2]));
  const float hw3 = C_VEC * log1pf(__expf(hwts[3]));

  int i = 0, j = 0;
  float4 bias = make_float4(0.f,0.f,0.f,0.f);
  if (p < ne){
    bias = *(const float4*)((const float*)rec + (size_t)p*16);
    const uint2 ij = *(const uint2*)(rec + (size_t)p*16 + 12);
    i = (int)ij.x; j = (int)ij.y;
  }

  if (full){
    const int l = tid & 63;
    const int c = l & 3, g = l >> 2;
    #pragma unroll
    for (int sb = 0; sb < 4; ++sb){
      const int el = sb*16 + g;
      const int ie = __shfl(i, el, 64);
      const int je = __shfl(j, el, 64);

      // scalar dot (heads from k-slice index, compile-time per it)
      const uint4* kr = (const uint4*)ks + (size_t)ie*32;
      const uint4* qr = (const uint4*)qs + (size_t)je*32;
      float s0=0.f, s1=0.f, s2=0.f, s3=0.f;
      #pragma unroll
      for (int it = 0; it < 8; ++it){
        const uint4 a = kr[it*4 + c];
        const uint4 b = qr[it*4 + c];
        float d;
        d  = bflo(a.x)*bflo(b.x) + bfhi(a.x)*bfhi(b.x);
        d += bflo(a.y)*bflo(b.y) + bfhi(a.y)*bfhi(b.y);
        d += bflo(a.z)*bflo(b.z) + bfhi(a.z)*bfhi(b.z);
        d += bflo(a.w)*bflo(b.w) + bfhi(a.w)*bfhi(b.w);
        if      (it < 2) s0 += d;
        else if (it < 4) s1 += d;
        else if (it < 6) s2 += d;
        else             s3 += d;
      }

      // vector attention (head = uint4-idx/3; uint4-idx = chunk*4+c)
      const uint4* qvr = (const uint4*)qv + (size_t)ie*12;
      const uint4* kvr = (const uint4*)kv + (size_t)je*12;
      float v0=0.f, v1=0.f, v2=0.f, v3=0.f;
      {
        const uint4 a = qvr[c], b = kvr[c];
        float d, t;
        t = bflo(a.x)-bflo(b.x); d  = t*t;  t = bfhi(a.x)-bfhi(b.x); d += t*t;
        t = bflo(a.y)-bflo(b.y); d += t*t;  t = bfhi(a.y)-bfhi(b.y); d += t*t;
        t = bflo(a.z)-bflo(b.z); d += t*t;  t = bfhi(a.z)-bfhi(b.z); d += t*t;
        t = bflo(a.w)-bflo(b.w); d += t*t;  t = bfhi(a.w)-bfhi(b.w); d += t*t;
        if (c < 3) v0 += d; else v1 += d;
      }
      {
        const uint4 a = qvr[4+c], b = kvr[4+c];
        float d, t;
        t = bflo(a.x)-bflo(b.x); d  = t*t;  t = bfhi(a.x)-bfhi(b.x); d += t*t;
        t = bflo(a.y)-bflo(b.y); d += t*t;  t = bfhi(a.y)-bfhi(b.y); d += t*t;
        t = bflo(a.z)-bflo(b.z); d += t*t;  t = bfhi(a.z)-bfhi(b.z); d += t*t;
        t = bflo(a.w)-bflo(b.w); d += t*t;  t = bfhi(a.w)-bfhi(b.w); d += t*t;
        if (c < 2) v1 += d; else v2 += d;
      }
      {
        const uint4 a = qvr[8+c], b = kvr[8+c];
        float d, t;
        t = bflo(a.x)-bflo(b.x); d  = t*t;  t = bfhi(a.x)-bfhi(b.x); d += t*t;
        t = bflo(a.y)-bflo(b.y); d += t*t;  t = bfhi(a.y)-bfhi(b.y); d += t*t;
        t = bflo(a.z)-bflo(b.z); d += t*t;  t = bfhi(a.z)-bfhi(b.z); d += t*t;
        t = bflo(a.w)-bflo(b.w); d += t*t;  t = bfhi(a.w)-bfhi(b.w); d += t*t;
        if (c < 1) v2 += d; else v3 += d;
      }

      // fold per-head partial logit, reduce across the 4 lanes of the group
      float p0 = C_SQRT83*s0 + hw0*v0;
      float p1 = C_SQRT83*s1 + hw1*v1;
      float p2 = C_SQRT83*s2 + hw2*v2;
      float p3 = C_SQRT83*s3 + hw3*v3;
      #pragma unroll
      for (int msk = 1; msk < 4; msk <<= 1){
        p0 += __shfl_xor(p0, msk, 64);
        p1 += __shfl_xor(p1, msk, 64);
        p2 += __shfl_xor(p2, msk, 64);
        p3 += __shfl_xor(p3, msk, 64);
      }
      const float pc = (c==0)?p0:((c==1)?p1:((c==2)?p2:p3));

      // route the 4 head-logits back to the owning lane (owners: l>>4 == sb)
      const int srcbase = (l & 15) << 2;
      const float q0 = __shfl(pc, srcbase+0, 64);
      const float q1 = __shfl(pc, srcbase+1, 64);
      const float q2 = __shfl(pc, srcbase+2, 64);
      const float q3 = __shfl(pc, srcbase+3, 64);
      if ((l >> 4) == sb){
        float4 lgv; lgv.x = q0 + bias.x; lgv.y = q1 + bias.y;
        lgv.z = q2 + bias.z; lgv.w = q3 + bias.w;
        *((float4*)lg + p) = lgv;                            // dense, coalesced
      }
    }
  } else if (p < ne){
    // tail block: per-thread gather (never hit when ne % 256 == 0)
    const uint4* kr = (const uint4*)ks + (size_t)i*32;
    const uint4* qr = (const uint4*)qs + (size_t)j*32;
    float sdot[4];
    #pragma unroll
    for (int h = 0; h < 4; ++h){
      float acc = 0.f;
      #pragma unroll
      for (int cc = 0; cc < 8; ++cc){
        const uint4 a = kr[h*8+cc];
        const uint4 b = qr[h*8+cc];
        acc += bflo(a.x)*bflo(b.x) + bfhi(a.x)*bfhi(b.x);
        acc += bflo(a.y)*bflo(b.y) + bfhi(a.y)*bfhi(b.y);
        acc += bflo(a.z)*bflo(b.z) + bfhi(a.z)*bfhi(b.z);
        acc += bflo(a.w)*bflo(b.w) + bfhi(a.w)*bfhi(b.w);
      }
      sdot[h] = acc;
    }
    const uint4* qvr = (const uint4*)qv + (size_t)i*12;
    const uint4* kvr = (const uint4*)kv + (size_t)j*12;
    float vsum[4];
    #pragma unroll
    for (int h = 0; h < 4; ++h){
      float acc = 0.f;
      #pragma unroll
      for (int cc = 0; cc < 3; ++cc){
        const uint4 a = qvr[h*3+cc];
        const uint4 b = kvr[h*3+cc];
        float d;
        d = bflo(a.x)-bflo(b.x); acc += d*d;  d = bfhi(a.x)-bfhi(b.x); acc += d*d;
        d = bflo(a.y)-bflo(b.y); acc += d*d;  d = bfhi(a.y)-bfhi(b.y); acc += d*d;
        d = bflo(a.z)-bflo(b.z); acc += d*d;  d = bfhi(a.z)-bfhi(b.z); acc += d*d;
        d = bflo(a.w)-bflo(b.w); acc += d*d;  d = bfhi(a.w)-bfhi(b.w); acc += d*d;
      }
      vsum[h] = acc;
    }
    float4 lgv;
    lgv.x = C_SQRT83*sdot[0] + bias.x + hw0*vsum[0];
    lgv.y = C_SQRT83*sdot[1] + bias.y + hw1*vsum[1];
    lgv.z = C_SQRT83*sdot[2] + bias.z + hw2*vsum[2];
    lgv.w = C_SQRT83*sdot[3] + bias.w + hw3*vsum[3];
    *((float4*)lg + p) = lgv;
  }
}

// ----------------------- wave-per-node softmax + pair -----------------------
// lg: dense E x float4 logits (coalesced stream).
// rec: bias at [0:4) (dead now), pz at [4:12), i,j at [12,13].

__global__ __launch_bounds__(256) void k_soft(
    const float* __restrict__ lg, const unsigned* __restrict__ rec,
    const unsigned* __restrict__ row_off, float* __restrict__ out_pair, int n)
{
  const int node = blockIdx.x*4 + (threadIdx.x >> 6);
  if (node >= n) return;
  const int lane = threadIdx.x & 63;
  const int beg = (int)row_off[node], end = (int)row_off[node+1];
  const float4* lg4 = (const float4*)lg;

  // ---- phase 1: per-head max and sum (lane-parallel over edges) ----
  float m[4] = {-3.0e38f,-3.0e38f,-3.0e38f,-3.0e38f};
  for (int p = beg + lane; p < end; p += 64){
    const float4 l = lg4[p];
    m[0]=fmaxf(m[0],l.x); m[1]=fmaxf(m[1],l.y); m[2]=fmaxf(m[2],l.z); m[3]=fmaxf(m[3],l.w);
  }
  #pragma unroll
  for (int msk = 1; msk < 64; msk <<= 1){
    #pragma unroll
    for (int h=0;h<4;h++) m[h] = fmaxf(m[h], __shfl_xor(m[h], msk));
  }
  float S[4] = {0.f,0.f,0.f,0.f};
  for (int p = beg + lane; p < end; p += 64){
    const float4 l = lg4[p];
    S[0]+=__expf(l.x-m[0]); S[1]+=__expf(l.y-m[1]);
    S[2]+=__expf(l.z-m[2]); S[3]+=__expf(l.w-m[3]);
  }
  #pragma unroll
  for (int msk = 1; msk < 64; msk <<= 1){
    #pragma unroll
    for (int h=0;h<4;h++) S[h] += __shfl_xor(S[h], msk);
  }
  float inv[4];
  #pragma unroll
  for (int h=0;h<4;h++) inv[h] = (S[h] > 0.f) ? (1.f/S[h]) : 0.f;

  // ---- phase 2: weighted pair aggregation ----
  const int e4 = lane >> 4, c = lane & 15;
  float acc[4] = {0.f,0.f,0.f,0.f};
  for (int base = beg; base < end; base += 4){
    const int p = base + e4;
    if (p < end){
      const float4 l = lg4[p];
      const unsigned u = rec[(size_t)p*16 + 4 + (c>>1)];
      const float pzv = (c & 1) ? bfhi(u) : bflo(u);
      acc[0] += __expf(l.x-m[0]) * pzv;
      acc[1] += __expf(l.y-m[1]) * pzv;
      acc[2] += __expf(l.z-m[2]) * pzv;
      acc[3] += __expf(l.w-m[3]) * pzv;
    }
  }
  #pragma unroll
  for (int msk = 16; msk < 64; msk <<= 1){
    #pragma unroll
    for (int h=0;h<4;h++) acc[h] += __shfl_xor(acc[h], msk);
  }
  const int hOut = lane >> 4;          // output layout: [h*16 + c]
  out_pair[(size_t)node*64 + lane] = acc[hOut] * inv[hOut];
}

// --------------------- feats assembly + output GEMM ------------------------
// 16 nodes/block: 28.7 KB LDS -> 5 blocks/CU (fixes 13% occupancy wall).

#define BNO 16

__global__ __launch_bounds__(256) void k_out(
    const float* __restrict__ vs, const float* __restrict__ vv,
    const float* __restrict__ out_pair, const unsigned* __restrict__ row_off,
    const float* __restrict__ quat, const float* __restrict__ trans,
    const float* __restrict__ Wout, const float* __restrict__ bout,
    float* __restrict__ out, int n)
{
  __shared__ float feats[BNO][448];
  __shared__ int degs[BNO];
  const int tid = threadIdx.x;
  const int node0 = blockIdx.x*BNO;

  if (tid < BNO){
    const int g = node0 + tid;
    degs[tid] = (g < n) ? (int)(row_off[g+1] - row_off[g]) : 1;
  }
  __syncthreads();

  for (int x = tid; x < BNO*256; x += 256){
    const int nd = x >> 8, c = x & 255;
    const int g = node0 + nd;
    feats[nd][c] = (g < n && degs[nd] > 0) ? vs[(size_t)g*256 + c] : 0.f;
  }
  for (int x = tid; x < BNO*64; x += 256){
    const int nd = x >> 6, c = x & 63;
    const int g = node0 + nd;
    feats[nd][384 + c] = (g < n) ? out_pair[(size_t)g*64 + c] : 0.f;
  }
  for (int x = tid; x < BNO*32; x += 256){
    const int nd = x >> 5, pt = x & 31;
    const int g = node0 + nd;
    float X=0.f, Y=0.f, Z=0.f;
    if (g < n){
      if (degs[nd] > 0){
        X = vv[(size_t)g*96 + pt];
        Y = vv[(size_t)g*96 + 32 + pt];
        Z = vv[(size_t)g*96 + 64 + pt];
      } else {
        const float4 q4 = *(const float4*)(quat + (size_t)g*4);
        const float tx = trans[(size_t)g*3], ty = trans[(size_t)g*3+1], tz = trans[(size_t)g*3+2];
        quat_rot(q4.x, -q4.y, -q4.z, -q4.w, -tx, -ty, -tz, X, Y, Z);
      }
    }
    feats[nd][256 + pt] = X;
    feats[nd][288 + pt] = Y;
    feats[nd][320 + pt] = Z;
    feats[nd][352 + pt] = sqrtf(X*X + Y*Y + Z*Z + 1e-8f);
  }
  __syncthreads();

  const int lane = tid & 63;
  const int wave = tid >> 6;
  float acc[4];
  #pragma unroll
  for (int q4=0;q4<4;q4++) acc[q4]=0.f;

  for (int k0 = 0; k0 < 448; k0 += 4){
    const float w0 = Wout[(size_t)(k0+0)*64 + lane];
    const float w1 = Wout[(size_t)(k0+1)*64 + lane];
    const float w2 = Wout[(size_t)(k0+2)*64 + lane];
    const float w3 = Wout[(size_t)(k0+3)*64 + lane];
    #pragma unroll
    for (int q4 = 0; q4 < 4; ++q4){
      const float4 f = *(const float4*)&feats[wave*4 + q4][k0];
      acc[q4] += f.x*w0 + f.y*w1 + f.z*w2 + f.w*w3;
    }
  }
  const float bo = bout[lane];
  #pragma unroll
  for (int q4 = 0; q4 < 4; ++q4){
    const int g = node0 + wave*4 + q4;
    if (g < n) out[(size_t)g*64 + lane] = acc[q4] + bo;
  }
}

// --------------------------------- launch ----------------------------------

extern "C" void kernel_launch(void* const* d_in, const int* in_sizes, int n_in,
                              void* d_out, int out_size, void* d_ws, size_t ws_size,
                              hipStream_t stream) {
  const float* s     = (const float*)d_in[0];
  const float* z     = (const float*)d_in[1];
  const int*   ei    = (const int*)  d_in[2];
  const float* quat  = (const float*)d_in[3];
  const float* trans = (const float*)d_in[4];
  const float* Wqs   = (const float*)d_in[5];
  const float* Wks   = (const float*)d_in[6];
  const float* Wvs   = (const float*)d_in[7];
  const float* Wqv   = (const float*)d_in[8];
  const float* Wkv   = (const float*)d_in[9];
  const float* Wvv   = (const float*)d_in[10];
  const float* Wb    = (const float*)d_in[11];
  const float* bb    = (const float*)d_in[12];
  const float* Wdz   = (const float*)d_in[13];
  const float* bdz   = (const float*)d_in[14];
  const float* hwts  = (const float*)d_in[15];
  const float* Wout  = (const float*)d_in[16];
  const float* bout  = (const float*)d_in[17];
  float* out = (float*)d_out;

  const int n  = in_sizes[0] / 64;   // 20000
  const int ne = in_sizes[1] / 64;   // 640000

  size_t off = 0;
  char* base = (char*)d_ws;
  auto take = [&](size_t bytes)->char* {
    char* p = base + off;
    off += (bytes + 255) & ~(size_t)255;
    return p;
  };
  unsigned* qs     = (unsigned*)take((size_t)n*512);    // bf16 N x 256
  unsigned* ks     = (unsigned*)take((size_t)n*512);    // bf16 N x 256
  unsigned* qvt    = (unsigned*)take((size_t)n*192);    // bf16 N x 96 (rot + t)
  unsigned* kvt    = (unsigned*)take((size_t)n*192);    // bf16 N x 96 (rot + t)
  float*    vs     = (float*)   take((size_t)n*1024);   // f32  N x 256
  float*    vv     = (float*)   take((size_t)n*384);    // f32  N x 96 (raw, planes)
  float*    lg     = (float*)   take((size_t)ne*16);    // f32  E x 4 dense logits
  unsigned* rec    = (unsigned*)take((size_t)ne*64);    // 64-B record per edge
  unsigned* counts = (unsigned*)take((size_t)n*4);
  unsigned* roff   = (unsigned*)take((size_t)(n+1)*4);
  unsigned* rank   = (unsigned*)take((size_t)ne*4);
  float*    opair  = (float*)   take((size_t)n*256);    // f32  N x 64
  (void)ws_size; (void)n_in; (void)out_size;

  const int gbE = (ne + 255) / 256;

  hipMemsetAsync(counts, 0, (size_t)n*4, stream);
  k_count<<<gbE, 256, 0, stream>>>(ei, counts, rank, ne);
  k_scan <<<1,   256, 0, stream>>>(counts, roff, n);
  k_proj <<<(n + BN - 1)/BN, 256, 0, stream>>>(s, quat, trans, Wqs, Wks, Wvs, Wqv, Wkv, Wvv,
                                               qs, ks, vs, qvt, kvt, vv, n);
  k_zf   <<<gbE, 256, 0, stream>>>(ei, rank, roff, z, Wb, bb, Wdz, bdz, rec, ne);
  k_edge <<<gbE, 256, 0, stream>>>(hwts, qs, ks, qvt, kvt, rec, lg, ne);
  k_soft <<<(n + 3)/4, 256, 0, stream>>>(lg, rec, roff, opair, n);
  k_out  <<<(n + BNO - 1)/BNO, 256, 0, stream>>>(vs, vv, opair, roff, quat, trans,
                                                 Wout, bout, out, n);
}